// Round 13
// baseline (831.544 us; speedup 1.0000x reference)
//
#include <hip/hip_runtime.h>
#include <hip/hip_bf16.h>
#include <math.h>

#define BB  32
#define NN  256
#define TT  256
#define WW  32
#define HH  128
#define EMBD 64
#define NCLS 16
#define NE  8192

__device__ __forceinline__ float bf(const __hip_bfloat16* p, int i) {
    return __bfloat162float(p[i]);
}
__device__ __forceinline__ float ld3(const void* p, int i, int m) {
    if (m == 2) return (float)((const double*)p)[i];
    if (m == 1) return ((const float*)p)[i];
    return __bfloat162float(((const __hip_bfloat16*)p)[i]);
}
__device__ __forceinline__ float r16(float x) {
    return __bfloat162float(__float2bfloat16(x));
}
__device__ __forceinline__ float tanh_s(float x) {
    x = fminf(20.0f, fmaxf(-20.0f, x));
    return tanhf(x);
}
__device__ __forceinline__ float sig_s(float x) {
    x = fminf(30.0f, fmaxf(-30.0f, x));
    return 1.0f / (1.0f + expf(-x));
}

// ---------------- guards / dtype detection ----------------

__global__ __launch_bounds__(64) void k_sentinel(float* out, float v) {
    int i = blockIdx.x * 64 + threadIdx.x;
    if (i < BB * NCLS) out[i] = v;
}

__global__ __launch_bounds__(256) void k_probe_all(
        const void* x, const void* ew, const void* Wg, const void* W1, const void* W2,
        const void* Wz, const void* Wr, const void* Wh, const void* Wlz, const void* Wlr,
        const void* Wlh, const void* Wc, int* insB, int* insF) {
    int sec = blockIdx.x >> 2, sub = blockIdx.x & 3;
    const void* p; int nB, idx;
    switch (sec) {
        case 0:  p = x;   nB = 32768; idx = 0;  break;
        case 1:  p = ew;  nB = 8192;  idx = 2;  break;
        case 2:  p = Wg;  nB = 10240; idx = 3;  break;
        case 3:  p = W1;  nB = 4096;  idx = 5;  break;
        case 4:  p = W2;  nB = 4096;  idx = 7;  break;
        case 5:  p = Wz;  nB = 4096;  idx = 9;  break;
        case 6:  p = Wr;  nB = 4096;  idx = 11; break;
        case 7:  p = Wh;  nB = 4096;  idx = 13; break;
        case 8:  p = Wlz; nB = 32768; idx = 15; break;
        case 9:  p = Wlr; nB = 32768; idx = 17; break;
        case 10: p = Wlh; nB = 32768; idx = 19; break;
        default: p = Wc;  nB = 32768; idx = 21; break;
    }
    int nF = nB >> 2;
    const __hip_bfloat16* pb = (const __hip_bfloat16*)p;
    const float* pf = (const float*)p;
    int start = sub * 256 + threadIdx.x;
    for (int i = start; i < nB; i += 1024) {
        float v = __bfloat162float(pb[i]);
        if (!(fabsf(v) < 64.0f)) { insB[idx] = 1; break; }
    }
    for (int i = start; i < nF; i += 1024) {
        float v = pf[i];
        if (!(fabsf(v) < 1e4f)) { insF[idx] = 1; break; }
    }
}

__global__ void k_resolve(const int* insB, const int* insF, int* modes) {
    int i = threadIdx.x;
    if (i < 32 && i != 1)
        modes[i] = insB[i] ? (insF[i] ? 2 : 1) : 0;
}

__global__ __launch_bounds__(64) void k_detect_ei(const int* ei, int* modes) {
    if (threadIdx.x == 0 && blockIdx.x == 0) {
        bool allz = true;
        for (int k = 1; k < 64; k += 2) if (ei[k] != 0) allz = false;
        modes[1] = allz ? 1 : 0;
    }
}

__global__ __launch_bounds__(256) void k_cvtall(const void* Wg, const void* W1, const void* W2,
                                                const void* Wz, const void* Wr, const void* Wh,
                                                const void* Wlz, const void* Wlr, const void* Wlh,
                                                const void* Wc, const int* modes, float* dst) {
    int i = blockIdx.x * 256 + threadIdx.x;
    if (i >= 665600) return;
    float v;
    if      (i < 10240)  v = ld3(Wg,  i,          modes[3]);
    else if (i < 14336)  v = ld3(W1,  i - 10240,  modes[5]);
    else if (i < 18432)  v = ld3(W2,  i - 14336,  modes[7]);
    else if (i < 22528)  v = ld3(Wz,  i - 18432,  modes[9]);
    else if (i < 26624)  v = ld3(Wr,  i - 22528,  modes[11]);
    else if (i < 30720)  v = ld3(Wh,  i - 26624,  modes[13]);
    else if (i < 63488)  v = ld3(Wlz, i - 30720,  modes[15]);
    else if (i < 96256)  v = ld3(Wlr, i - 63488,  modes[17]);
    else if (i < 129024) v = ld3(Wlh, i - 96256,  modes[19]);
    else if (i < 653312) v = ld3(Wc,  i - 129024, modes[21]);
    else {
        int j = i - 653312, w = j / 384, rem = j - w * 384;
        int g = rem >> 7, f = rem & 127;
        const void* Wk = (g == 0) ? Wz : ((g == 1) ? Wr : Wh);
        int mk = (g == 0) ? modes[9] : ((g == 1) ? modes[11] : modes[13]);
        v = ld3(Wk, w * 128 + f, mk);
    }
    dst[i] = v;
}

// k_fuse: build fused GRU weights/biases.
// Wf layout [3][160][128]: rows 0..31 = W_g@Wl_top, rows 32..159 = Wl_bot. bfv [3][128].
__global__ __launch_bounds__(256) void k_fuse(const float* Wzf, const float* Wrf, const float* Whf,
                                              const float* Wlzf, const float* Wlrf, const float* Wlhf,
                                              const __hip_bfloat16* bz, const __hip_bfloat16* br,
                                              const __hip_bfloat16* bh,
                                              const __hip_bfloat16* blz, const __hip_bfloat16* blr,
                                              const __hip_bfloat16* blh,
                                              float* Wf, float* bfv) {
    int g = blockIdx.y;
    const float* Wcv = (g == 0) ? Wzf : ((g == 1) ? Wrf : Whf);
    const float* Wl  = (g == 0) ? Wlzf : ((g == 1) ? Wlrf : Wlhf);
    const __hip_bfloat16* bcv = (g == 0) ? bz : ((g == 1) ? br : bh);
    const __hip_bfloat16* blv = (g == 0) ? blz : ((g == 1) ? blr : blh);
    int idx = blockIdx.x * 256 + threadIdx.x;
    if (idx >= 160 * 128) return;
    int k = idx >> 7, f = idx & 127;
    float v;
    if (k < 32) {
        float acc = 0.f;
        for (int m = 0; m < 128; m++) acc += Wcv[k * 128 + m] * Wl[m * 128 + f];
        v = acc;
    } else {
        v = Wl[(k + 96) * 128 + f];
    }
    Wf[((size_t)g * 160 + k) * 128 + f] = v;
    if (idx < 128) {
        float acc = __bfloat162float(blv[idx]);
        for (int m = 0; m < 128; m++) acc += __bfloat162float(bcv[m]) * Wl[m * 128 + idx];
        bfv[g * 128 + idx] = acc;
    }
}

// ---------------- setup: bf16 static graph ----------------

__global__ __launch_bounds__(256) void k_scatter(const int* ei, const void* ew, float* A,
                                                 const int* modes) {
    int e = blockIdx.x * 256 + threadIdx.x;
    if (e < NE) {
        int s, t;
        if (modes[1]) { s = ei[2 * e]; t = ei[2 * (NE + e)]; }
        else          { s = ei[e];     t = ei[NE + e]; }
        float w = r16(ld3(ew, e, modes[2]));
        if ((unsigned)s < NN && (unsigned)t < NN)
            atomicAdd(&A[s * NN + t], w);
    }
    if (blockIdx.x == 0) atomicAdd(&A[threadIdx.x * NN + threadIdx.x], 1.0f);
}

__global__ __launch_bounds__(256) void k_roundA(float* A) {
    int i = blockIdx.x * 256 + threadIdx.x;
    A[i] = r16(A[i]);
}

__global__ __launch_bounds__(256) void k_di(const float* A, float* di) {
    int wave = threadIdx.x >> 6, lane = threadIdx.x & 63;
    int c = blockIdx.x * 4 + wave;
    float s = 0.f;
    for (int r = lane; r < NN; r += 64) s += A[r * NN + c];
    for (int o = 32; o > 0; o >>= 1) s += __shfl_down(s, o, 64);
    if (lane == 0) {
        float deg = r16(s);
        di[c] = (deg > 0.f) ? r16(1.0f / sqrtf(deg)) : 0.0f;
    }
}

__global__ __launch_bounds__(256) void k_St(const float* A, const float* di, float* St) {
    int idx = blockIdx.x * 256 + threadIdx.x; // idx = c*NN + r
    int c = idx >> 8, r = idx & 255;
    St[idx] = r16(r16(di[r] * A[r * NN + c]) * di[c]);
}

// ---------------- per-step ----------------

// k1: Y = [vt|h] @ Wg. Used only for t=0 (h=0). 4 nodes per 256-thread block.
__global__ __launch_bounds__(256) void k1_itwg4(const void* x, const float* h,
                                                const float* Wgf, float* Y,
                                                int t, const int* modes) {
    __shared__ float vt[4][32];
    __shared__ float hr[4][128];
    int b = blockIdx.y, n0 = blockIdx.x * 4;
    int tid = threadIdx.x;
    int nd = tid >> 6, f = tid & 63;
    if (f < WW) vt[nd][f] = ld3(x, (b * NN + n0 + nd) * TT + t * WW + f, modes[0]);
    size_t hb = (size_t)(b * NN + n0 + nd) * HH;
    hr[nd][f] = h[hb + f];
    hr[nd][f + 64] = h[hb + f + 64];
    __syncthreads();
    float acc = 0.f;
    for (int k = 0; k < WW; k++)  acc += vt[nd][k] * Wgf[k * EMBD + f];
    for (int k = 0; k < HH; k++)  acc += hr[nd][k] * Wgf[(WW + k) * EMBD + f];
    if (t == 0 && modes[0] == 0 && modes[3] == 0) acc = r16(acc);
    Y[(size_t)(b * NN + n0 + nd) * EMBD + f] = acc;
}

// k23h: fused k2+k3 at 2 blocks/CU. 16 c-rows x 64 f per block. grid (16, BB).
__global__ __launch_bounds__(256) void k23h(const float* St, const float* Y,
                                            const __hip_bfloat16* bg,
                                            const float* W1f, const float* W2f,
                                            const __hip_bfloat16* b1, const __hip_bfloat16* b2,
                                            float* de1, float* de2, float* qsum,
                                            int t, const int* modes) {
    __shared__ float AsT[32 * 18];   // St^T slab [k][c], stride 18 (b64-aligned pairs)
    __shared__ float Bs[32 * 68];    // [k][f]
    __shared__ float dfT[64 * 18];   // [f][c]
    int b = blockIdx.y, c0 = blockIdx.x * 16;
    int tid = threadIdx.x;
    if (blockIdx.x == 0) qsum[b * NN + tid] = 0.f;
    int rg = tid >> 5;        // 0-7  -> c-rows rg*2+i
    int cg = tid & 31;        // 0-31 -> f-cols cg*2+j
    const float* Yb = Y + (size_t)b * (NN * EMBD);
    float acc[2][2] = {};
    for (int kb = 0; kb < 256; kb += 32) {
        if (tid < 128) {
            int c = tid >> 3, k4 = (tid & 7) * 4;
            float4 sv = *(const float4*)(St + (size_t)(c0 + c) * 256 + kb + k4);
            AsT[(k4 + 0) * 18 + c] = sv.x;
            AsT[(k4 + 1) * 18 + c] = sv.y;
            AsT[(k4 + 2) * 18 + c] = sv.z;
            AsT[(k4 + 3) * 18 + c] = sv.w;
        }
        {
            int bk = tid >> 3, bn0 = (tid & 7) * 8;
            const float* bp = Yb + (size_t)(kb + bk) * 64 + bn0;
            *(float4*)&Bs[bk * 68 + bn0]     = *(const float4*)bp;
            *(float4*)&Bs[bk * 68 + bn0 + 4] = *(const float4*)(bp + 4);
        }
        __syncthreads();
#pragma unroll 4
        for (int kk = 0; kk < 32; kk++) {
            float2 av = *(const float2*)&AsT[kk * 18 + rg * 2];
            float2 bv = *(const float2*)&Bs[kk * 68 + cg * 2];
            acc[0][0] += av.x * bv.x; acc[0][1] += av.x * bv.y;
            acc[1][0] += av.y * bv.x; acc[1][1] += av.y * bv.y;
        }
        __syncthreads();
    }
    bool rnd = (t == 0 && modes[0] == 0 && modes[3] == 0);
#pragma unroll
    for (int i = 0; i < 2; i++)
#pragma unroll
        for (int j = 0; j < 2; j++) {
            int f = cg * 2 + j;
            float v = (rnd ? r16(acc[i][j]) : acc[i][j]) + bf(bg, f);
            dfT[f * 18 + rg * 2 + i] = v;
        }
    __syncthreads();
    // de1 = tanh(dfT^T @ W1 + b1)
    float a1[2][2] = {};
    for (int kb2 = 0; kb2 < 64; kb2 += 32) {
        int bk = tid >> 3, bn0 = (tid & 7) * 8;
        const float* bp = W1f + (size_t)(kb2 + bk) * 64 + bn0;
        *(float4*)&Bs[bk * 68 + bn0]     = *(const float4*)bp;
        *(float4*)&Bs[bk * 68 + bn0 + 4] = *(const float4*)(bp + 4);
        __syncthreads();
#pragma unroll 4
        for (int kk = 0; kk < 32; kk++) {
            float2 av = *(const float2*)&dfT[(kb2 + kk) * 18 + rg * 2];
            float2 bv = *(const float2*)&Bs[kk * 68 + cg * 2];
            a1[0][0] += av.x * bv.x; a1[0][1] += av.x * bv.y;
            a1[1][0] += av.y * bv.x; a1[1][1] += av.y * bv.y;
        }
        __syncthreads();
    }
#pragma unroll
    for (int i = 0; i < 2; i++) {
        int row = b * NN + c0 + rg * 2 + i;
        float2 o;
        o.x = tanh_s(a1[i][0] + bf(b1, cg * 2 + 0));
        o.y = tanh_s(a1[i][1] + bf(b1, cg * 2 + 1));
        *(float2*)&de1[(size_t)row * 64 + cg * 2] = o;
    }
    // de2 = tanh(dfT^T @ W2 + b2)
    float a2[2][2] = {};
    for (int kb2 = 0; kb2 < 64; kb2 += 32) {
        int bk = tid >> 3, bn0 = (tid & 7) * 8;
        const float* bp = W2f + (size_t)(kb2 + bk) * 64 + bn0;
        *(float4*)&Bs[bk * 68 + bn0]     = *(const float4*)bp;
        *(float4*)&Bs[bk * 68 + bn0 + 4] = *(const float4*)(bp + 4);
        __syncthreads();
#pragma unroll 4
        for (int kk = 0; kk < 32; kk++) {
            float2 av = *(const float2*)&dfT[(kb2 + kk) * 18 + rg * 2];
            float2 bv = *(const float2*)&Bs[kk * 68 + cg * 2];
            a2[0][0] += av.x * bv.x; a2[0][1] += av.x * bv.y;
            a2[1][0] += av.y * bv.x; a2[1][1] += av.y * bv.y;
        }
        __syncthreads();
    }
#pragma unroll
    for (int i = 0; i < 2; i++) {
        int row = b * NN + c0 + rg * 2 + i;
        float2 o;
        o.x = tanh_s(a2[i][0] + bf(b2, cg * 2 + 0));
        o.y = tanh_s(a2[i][1] + bf(b2, cg * 2 + 1));
        *(float2*)&de2[(size_t)row * 64 + cg * 2] = o;
    }
}

// k45: fused M+Et+hist+AhT+qsum. grid (4,4,BB): r0=bx*64, c0=by*64.
// R13: diagonal blocks (r0==c0) skip GEMM-A; M2 content == M1 there (same
// products, same k-order) so m2b is filled from acc1 -> bit-identical.
__global__ __launch_bounds__(256) void k45(const float* de1, const float* de2,
                                           float* hist, float* AhT, float* qsum,
                                           int slabW, int slabR, float inv_cnt) {
    __shared__ float As[32][68];
    __shared__ float Bs[32][68];
    __shared__ float m2b[64][65];
    __shared__ float qpart[64];
    int b = blockIdx.z, r0 = blockIdx.x * 64, c0 = blockIdx.y * 64;
    int tid = threadIdx.x;
    if (tid < 64) qpart[tid] = 0.f;
    int tn = tid & 15, tm = tid >> 4;
    int am = tid >> 2, ak0 = (tid & 3) * 8;
    int rot = (tid & 3) * 2;
    const float* d1 = de1 + (size_t)b * (NN * EMBD);
    const float* d2 = de2 + (size_t)b * (NN * EMBD);
    bool diag = (r0 == c0);
    if (!diag) {
        // GEMM-A: M2[cl][rl] = de1[c0+cl]·de2[r0+rl]
        float acc2[4][4] = {};
        for (int kb = 0; kb < 64; kb += 32) {
            const float* ap = d1 + (size_t)(c0 + am) * 64 + kb + ak0;
            float4 a0 = *(const float4*)ap;
            float4 a1 = *(const float4*)(ap + 4);
            float av8[8] = {a0.x, a0.y, a0.z, a0.w, a1.x, a1.y, a1.z, a1.w};
#pragma unroll
            for (int jj = 0; jj < 8; jj++) { int j = (jj + rot) & 7; As[ak0 + j][am] = av8[j]; }
            const float* bp = d2 + (size_t)(r0 + am) * 64 + kb + ak0;
            float4 b0 = *(const float4*)bp;
            float4 b1v = *(const float4*)(bp + 4);
            float bv8[8] = {b0.x, b0.y, b0.z, b0.w, b1v.x, b1v.y, b1v.z, b1v.w};
#pragma unroll
            for (int jj = 0; jj < 8; jj++) { int j = (jj + rot) & 7; Bs[ak0 + j][am] = bv8[j]; }
            __syncthreads();
#pragma unroll
            for (int kk = 0; kk < 32; kk++) {
                float4 av = *(const float4*)&As[kk][tm * 4];
                float4 bv = *(const float4*)&Bs[kk][tn * 4];
                float aa[4] = {av.x, av.y, av.z, av.w};
                float bb[4] = {bv.x, bv.y, bv.z, bv.w};
#pragma unroll
                for (int i = 0; i < 4; i++)
#pragma unroll
                    for (int j = 0; j < 4; j++) acc2[i][j] += aa[i] * bb[j];
            }
            __syncthreads();
        }
#pragma unroll
        for (int i = 0; i < 4; i++)
#pragma unroll
            for (int j = 0; j < 4; j++) m2b[tm * 4 + i][tn * 4 + j] = acc2[i][j];
    }
    // GEMM-B: M1[rl][cl] = de1[r0+rl]·de2[c0+cl]
    float acc1[4][4] = {};
    for (int kb = 0; kb < 64; kb += 32) {
        const float* ap = d1 + (size_t)(r0 + am) * 64 + kb + ak0;
        float4 a0 = *(const float4*)ap;
        float4 a1 = *(const float4*)(ap + 4);
        float av8[8] = {a0.x, a0.y, a0.z, a0.w, a1.x, a1.y, a1.z, a1.w};
#pragma unroll
        for (int jj = 0; jj < 8; jj++) { int j = (jj + rot) & 7; As[ak0 + j][am] = av8[j]; }
        const float* bp = d2 + (size_t)(c0 + am) * 64 + kb + ak0;
        float4 b0 = *(const float4*)bp;
        float4 b1v = *(const float4*)(bp + 4);
        float bv8[8] = {b0.x, b0.y, b0.z, b0.w, b1v.x, b1v.y, b1v.z, b1v.w};
#pragma unroll
        for (int jj = 0; jj < 8; jj++) { int j = (jj + rot) & 7; Bs[ak0 + j][am] = bv8[j]; }
        __syncthreads();
#pragma unroll
        for (int kk = 0; kk < 32; kk++) {
            float4 av = *(const float4*)&As[kk][tm * 4];
            float4 bv = *(const float4*)&Bs[kk][tn * 4];
            float aa[4] = {av.x, av.y, av.z, av.w};
            float bb[4] = {bv.x, bv.y, bv.z, bv.w};
#pragma unroll
            for (int i = 0; i < 4; i++)
#pragma unroll
                for (int j = 0; j < 4; j++) acc1[i][j] += aa[i] * bb[j];
        }
        __syncthreads();
    }
    if (diag) {
        // m2b = M1 (content identical to what GEMM-A would compute on the diagonal)
#pragma unroll
        for (int i = 0; i < 4; i++)
#pragma unroll
            for (int j = 0; j < 4; j++) m2b[tm * 4 + i][tn * 4 + j] = acc1[i][j];
        __syncthreads();   // epilogue reads m2b transposed (cross-thread)
    }
    // Et + hist roll + ad; hist I/O float4 along c
    size_t NB = (size_t)BB * NN * NN;
    float* hsW = hist + (size_t)slabW * NB;
    const float* hsR = hist + (size_t)slabR * NB;
    float ad[4][4];
#pragma unroll
    for (int i = 0; i < 4; i++) {
        int r = r0 + tm * 4 + i;
        size_t o = ((size_t)(b * NN + r)) * NN + c0 + tn * 4;
        float4 e2v = *(const float4*)&hsW[o];
        float4 e1v = *(const float4*)&hsR[o];
        float e2a[4] = {e2v.x, e2v.y, e2v.z, e2v.w};
        float e1a[4] = {e1v.x, e1v.y, e1v.z, e1v.w};
        float4 ew4;
        float eo[4];
#pragma unroll
        for (int j = 0; j < 4; j++) {
            int c = c0 + tn * 4 + j;
            float e = tanh_s(acc1[i][j] - m2b[tn * 4 + j][tm * 4 + i]);
            e = e > 0.f ? e : 0.f;
            eo[j] = e;
            float mt = (e + e1a[j] + e2a[j]) * inv_cnt;
            float adv = (mt > 1e-8f) ? mt : 0.f;
            if (r == c) adv += 1.f;
            ad[i][j] = adv;
        }
        ew4.x = eo[0]; ew4.y = eo[1]; ew4.z = eo[2]; ew4.w = eo[3];
        *(float4*)&hsW[o] = ew4;
    }
    // qsum partials: column sums over this tile's rows
#pragma unroll
    for (int j = 0; j < 4; j++) {
        float cs = ad[0][j] + ad[1][j] + ad[2][j] + ad[3][j];
        atomicAdd(&qpart[tn * 4 + j], cs);
    }
    // stage ad transposed for coalesced AhT write (reuse m2b after all reads)
    __syncthreads();
#pragma unroll
    for (int i = 0; i < 4; i++)
#pragma unroll
        for (int j = 0; j < 4; j++) m2b[tn * 4 + j][tm * 4 + i] = ad[i][j];
    __syncthreads();
#pragma unroll
    for (int kk = 0; kk < 4; kk++) {
        int e = tid + kk * 256;
        int cl = e >> 4, q4 = e & 15;
        float4 o;
        o.x = m2b[cl][q4 * 4 + 0]; o.y = m2b[cl][q4 * 4 + 1];
        o.z = m2b[cl][q4 * 4 + 2]; o.w = m2b[cl][q4 * 4 + 3];
        *(float4*)&AhT[((size_t)(b * NN + c0 + cl)) * NN + r0 + q4 * 4] = o;
    }
    if (tid < 64) atomicAdd(&qsum[b * NN + c0 + tid], qpart[tid]);
}

// kZRH16: fused G + GRU + next-step Y. grid 512: 16 rows/block (2 blocks/CU).
// R13: gates use a thread-role split (half Z, half R) with 4r x 4c tiles:
// per kk one b128 A-read + one b128 B-read per 16 FMA (1.5 cyc/FMA vs 2.0).
// Z passes to h-update via zbuf LDS. A^T stride 18 -> 20 (b128-aligned rows).
// Each output element still accumulates k ascending -> bit-identical.
__global__ __launch_bounds__(256) void kZRH16(const float* AhT, const float* qsum, float* h,
                                              const float* Wf, const float* bfv,
                                              const float* Wgf, const void* x, float* Y,
                                              int t, const int* modes) {
    __shared__ float qrow[256];
    __shared__ float As[160 * 20];   // [k][row], 16 rows, stride 20
    __shared__ float Bs[8448];       // union: ph0 vtqT[32*132]+Ah[16*132]; gates 2 panels
    __shared__ float zbuf[16 * 128];
    int r0 = blockIdx.x * 16;        // global row (b*NN + n)
    int b  = r0 >> 8;
    int tid = threadIdx.x;
    int m0 = modes[0];
    // stage h^T: h[r0+r][c] -> As[(32+c)*20 + r]
#pragma unroll
    for (int u = 0; u < 2; u++) {
        int e = tid * 2 + u;
        int r = e >> 5, c4 = (e & 31) * 4;
        float4 hv = *(const float4*)&h[(size_t)(r0 + r) * 128 + c4];
        As[(32 + c4 + 0) * 20 + r] = hv.x;
        As[(32 + c4 + 1) * 20 + r] = hv.y;
        As[(32 + c4 + 2) * 20 + r] = hv.z;
        As[(32 + c4 + 3) * 20 + r] = hv.w;
    }
    qrow[tid] = 1.0f / sqrtf(fmaxf(qsum[b * NN + tid], 1e-12f));
    __syncthreads();

    // ---- phase 0: G into As G-region ----
    {
        float* vtq = Bs;            // [32 w][132 r]
        float* Ah  = Bs + 4224;     // [16][132]
        float gacc[2] = {0.f, 0.f};
        int gi = tid & 15, gw = (tid >> 4) * 2;
        for (int half = 0; half < 2; half++) {
            int wv = tid & 31, rb = tid >> 5;
#pragma unroll
            for (int k = 0; k < 16; k++) {
                int rl = rb + 8 * k;
                int rg = half * 128 + rl;
                vtq[wv * 132 + rl] = qrow[rg] * ld3(x, (b * NN + rg) * TT + t * WW + wv, m0);
            }
            {
                int i = tid >> 4, c8 = (tid & 15) * 8;
                const float* ap = AhT + (size_t)(r0 + i) * NN + half * 128 + c8;
                *(float4*)&Ah[i * 132 + c8]     = *(const float4*)ap;
                *(float4*)&Ah[i * 132 + c8 + 4] = *(const float4*)(ap + 4);
            }
            __syncthreads();
            for (int r = 0; r < 128; r += 4) {
                float4 a  = *(const float4*)&Ah[gi * 132 + r];
                float4 v0 = *(const float4*)&vtq[gw * 132 + r];
                float4 v1 = *(const float4*)&vtq[(gw + 1) * 132 + r];
                gacc[0] += a.x * v0.x;
                gacc[1] += a.x * v1.x;
                gacc[0] += a.y * v0.y;
                gacc[1] += a.y * v1.y;
                gacc[0] += a.z * v0.z;
                gacc[1] += a.z * v1.z;
                gacc[0] += a.w * v0.w;
                gacc[1] += a.w * v1.w;
            }
            __syncthreads();
        }
        float qc = qrow[(r0 & 255) + gi];
        As[gw * 20 + gi]       = qc * gacc[0];
        As[(gw + 1) * 20 + gi] = qc * gacc[1];
        // gates stage Bs then sync before reading As G-region
    }

    // ---- gates: role-split. tid<128 -> Z, tid>=128 -> R. 4r x 4c tiles. ----
    {
        int gsel = tid >> 7;                 // 0 = Z, 1 = R
        int rt = (tid >> 5) & 3;             // rows rt*4+i
        int ct = tid & 31;                   // cols ct*4+j
        const float* W0 = Wf;
        const float* W1 = Wf + (size_t)(160 * 128);
        float accG[4][4] = {};
        for (int kb = 0; kb < 160; kb += 32) {
#pragma unroll
            for (int u = 0; u < 4; u++) {
                int e = tid + u * 256;
                int kk = e >> 5, c4 = (e & 31) * 4;
                *(float4*)&Bs[kk * 128 + c4]        = *(const float4*)&W0[(size_t)(kb + kk) * 128 + c4];
                *(float4*)&Bs[4096 + kk * 128 + c4] = *(const float4*)&W1[(size_t)(kb + kk) * 128 + c4];
            }
            __syncthreads();
            const float* Bp = Bs + gsel * 4096;
#pragma unroll 4
            for (int kk = 0; kk < 32; kk++) {
                float4 av = *(const float4*)&As[(kb + kk) * 20 + rt * 4];
                float4 bv = *(const float4*)&Bp[kk * 128 + ct * 4];
                accG[0][0] += av.x * bv.x; accG[0][1] += av.x * bv.y;
                accG[0][2] += av.x * bv.z; accG[0][3] += av.x * bv.w;
                accG[1][0] += av.y * bv.x; accG[1][1] += av.y * bv.y;
                accG[1][2] += av.y * bv.z; accG[1][3] += av.y * bv.w;
                accG[2][0] += av.z * bv.x; accG[2][1] += av.z * bv.y;
                accG[2][2] += av.z * bv.z; accG[2][3] += av.z * bv.w;
                accG[3][0] += av.w * bv.x; accG[3][1] += av.w * bv.y;
                accG[3][2] += av.w * bv.z; accG[3][3] += av.w * bv.w;
            }
            __syncthreads();
        }
        if (gsel == 0) {
            // Z -> zbuf
#pragma unroll
            for (int i = 0; i < 4; i++)
#pragma unroll
                for (int j = 0; j < 4; j++)
                    zbuf[(rt * 4 + i) * 128 + ct * 4 + j] =
                        sig_s(accG[i][j] + bfv[ct * 4 + j]);
        } else {
            // R -> hR in place (each slot owned by exactly one thread)
#pragma unroll
            for (int i = 0; i < 4; i++)
#pragma unroll
                for (int j = 0; j < 4; j++) {
                    float rv = sig_s(accG[i][j] + bfv[128 + ct * 4 + j]);
                    int slot = (32 + ct * 4 + j) * 20 + rt * 4 + i;
                    As[slot] = As[slot] * rv;
                }
        }
        // next phase's staging + sync orders these writes before any read
    }

    int rg = tid >> 5, cg = tid & 31;   // 2r x 4c for Ht / h-update
    // ---- Ht GEMM over [G|hR] (panel 0 of Bs) ----
    float acc[2][4] = {};
    {
        const float* Wgp = Wf + (size_t)2 * (160 * 128);
        for (int kb = 0; kb < 160; kb += 32) {
#pragma unroll
            for (int u = 0; u < 4; u++) {
                int e = tid + u * 256;
                int kk = e >> 5, c4 = (e & 31) * 4;
                *(float4*)&Bs[kk * 128 + c4] = *(const float4*)&Wgp[(size_t)(kb + kk) * 128 + c4];
            }
            __syncthreads();
#pragma unroll 4
            for (int kk = 0; kk < 32; kk++) {
                float2 av = *(const float2*)&As[(kb + kk) * 20 + rg * 2];
                float4 bv = *(const float4*)&Bs[kk * 128 + cg * 4];
                acc[0][0] += av.x * bv.x; acc[0][1] += av.x * bv.y;
                acc[0][2] += av.x * bv.z; acc[0][3] += av.x * bv.w;
                acc[1][0] += av.y * bv.x; acc[1][1] += av.y * bv.y;
                acc[1][2] += av.y * bv.z; acc[1][3] += av.y * bv.w;
            }
            __syncthreads();
        }
    }
    // ---- h-update; write h global + refresh As h-region with h_new ----
#pragma unroll
    for (int i = 0; i < 2; i++) {
        int row = r0 + rg * 2 + i;
        size_t o = (size_t)row * 128 + cg * 4;
        float4 hv = *(const float4*)&h[o];       // h_old (global still intact)
        float4 zq = *(const float4*)&zbuf[(rg * 2 + i) * 128 + cg * 4];
        float4 r;
        r.x = zq.x * hv.x + (1.0f - zq.x) * tanh_s(acc[i][0] + bfv[256 + cg * 4 + 0]);
        r.y = zq.y * hv.y + (1.0f - zq.y) * tanh_s(acc[i][1] + bfv[256 + cg * 4 + 1]);
        r.z = zq.z * hv.z + (1.0f - zq.z) * tanh_s(acc[i][2] + bfv[256 + cg * 4 + 2]);
        r.w = zq.w * hv.w + (1.0f - zq.w) * tanh_s(acc[i][3] + bfv[256 + cg * 4 + 3]);
        *(float4*)&h[o] = r;
        As[(32 + cg * 4 + 0) * 20 + rg * 2 + i] = r.x;
        As[(32 + cg * 4 + 1) * 20 + rg * 2 + i] = r.y;
        As[(32 + cg * 4 + 2) * 20 + rg * 2 + i] = r.z;
        As[(32 + cg * 4 + 3) * 20 + rg * 2 + i] = r.w;
    }
    // ---- next-step Y = [vt(t+1)|h_new] @ Wgf ----
    if (t < 7) {
        // stage vt2^T into the dead G-region (all As reads finished before last sync)
#pragma unroll
        for (int u = 0; u < 2; u++) {
            int e = tid * 2 + u;
            int r = e >> 5, w = e & 31;
            As[w * 20 + r] = ld3(x, (r0 + r) * TT + (t + 1) * WW + w, m0);
        }
        __syncthreads();
        int yr = tid >> 4, yc4 = (tid & 15) * 4;
        float yacc[4] = {0.f, 0.f, 0.f, 0.f};
        for (int kb = 0; kb < 160; kb += 32) {
#pragma unroll
            for (int u = 0; u < 2; u++) {
                int e = tid * 2 + u;
                int kk = e >> 4, c4 = (e & 15) * 4;
                *(float4*)&Bs[kk * 64 + c4] = *(const float4*)&Wgf[(size_t)(kb + kk) * 64 + c4];
            }
            __syncthreads();
#pragma unroll 4
            for (int kk = 0; kk < 32; kk++) {
                float a = As[(kb + kk) * 20 + yr];
                float4 bv = *(const float4*)&Bs[kk * 64 + yc4];
                yacc[0] += a * bv.x; yacc[1] += a * bv.y;
                yacc[2] += a * bv.z; yacc[3] += a * bv.w;
            }
            __syncthreads();
        }
        *(float4*)&Y[(size_t)(r0 + yr) * 64 + yc4] =
            make_float4(yacc[0], yacc[1], yacc[2], yacc[3]);
    }
}

__global__ __launch_bounds__(256) void k10a(const float* h, const float* Wcf, float* partial) {
    __shared__ float red[16][17];
    int chunk = blockIdx.x, b = blockIdx.y;
    int c = threadIdx.x & 15, isub = threadIdx.x >> 4;
    const float* hb = h + (size_t)b * (NN * HH);
    int i0 = chunk * 2048;
    float acc = 0.f;
    for (int s = 0; s < 128; s++) {
        int i = i0 + isub + 16 * s;
        acc += hb[i] * Wcf[(size_t)i * NCLS + c];
    }
    red[isub][c] = acc;
    __syncthreads();
    for (int st = 8; st > 0; st >>= 1) {
        if (isub < st) red[isub][c] += red[isub + st][c];
        __syncthreads();
    }
    if (isub == 0) partial[((size_t)(b * NCLS + c)) * 16 + chunk] = red[0][c];
}

__global__ __launch_bounds__(512) void k10b(const float* partial, const __hip_bfloat16* bcb,
                                            float* out) {
    int tid = threadIdx.x;
    if (tid < BB * NCLS) {
        int c = tid & 15;
        float s = 0.f;
        for (int k = 0; k < 16; k++) s += partial[(size_t)tid * 16 + k];
        out[tid] = s + bf(bcb, c);
    }
}

// ---------------- launch ----------------

extern "C" void kernel_launch(void* const* d_in, const int* in_sizes, int n_in,
                              void* d_out, int out_size, void* d_ws, size_t ws_size,
                              hipStream_t stream) {
    float* out = (float*)d_out;

    static const int exp_sizes[23] = {2097152, 16384, 8192, 10240, 64, 4096, 64, 4096, 64,
                                      4096, 128, 4096, 128, 4096, 128, 32768, 128, 32768, 128,
                                      32768, 128, 524288, 16};
    if (n_in != 23) { k_sentinel<<<8, 64, 0, stream>>>(out, 4444.0f); return; }
    for (int i = 0; i < 23; i++) {
        if (in_sizes[i] != exp_sizes[i]) {
            k_sentinel<<<8, 64, 0, stream>>>(out, (float)(4000 + i));
            return;
        }
    }

    const void* x   = d_in[0];
    const int*  ei  = (const int*)d_in[1];
    const void* ew  = d_in[2];
    const void* Wg  = d_in[3];
    const __hip_bfloat16* bg  = (const __hip_bfloat16*)d_in[4];
    const void* W1  = d_in[5];
    const __hip_bfloat16* b1  = (const __hip_bfloat16*)d_in[6];
    const void* W2  = d_in[7];
    const __hip_bfloat16* b2  = (const __hip_bfloat16*)d_in[8];
    const void* Wz  = d_in[9];
    const __hip_bfloat16* bz  = (const __hip_bfloat16*)d_in[10];
    const void* Wr  = d_in[11];
    const __hip_bfloat16* br  = (const __hip_bfloat16*)d_in[12];
    const void* Wh  = d_in[13];
    const __hip_bfloat16* bh  = (const __hip_bfloat16*)d_in[14];
    const void* Wlz = d_in[15];
    const __hip_bfloat16* blz = (const __hip_bfloat16*)d_in[16];
    const void* Wlr = d_in[17];
    const __hip_bfloat16* blr = (const __hip_bfloat16*)d_in[18];
    const void* Wlh = d_in[19];
    const __hip_bfloat16* blh = (const __hip_bfloat16*)d_in[20];
    const void* Wc  = d_in[21];
    const __hip_bfloat16* bcb = (const __hip_bfloat16*)d_in[22];

    float* ws = (float*)d_ws;
    const size_t off_A    = 0;                          // 65536
    const size_t off_hist = off_A + 65536;              // 2*2097152
    const size_t off_h    = off_hist + 2u * 2097152;    // 1048576
    const size_t off_flag = off_h + 1048576;            // 16
    const size_t off_mode = off_flag + 16;              // 32
    const size_t off_insB = off_mode + 32;              // 32
    const size_t off_insF = off_insB + 32;              // 32
    const size_t zero_end = off_insF + 32;
    const size_t off_St   = zero_end;                   // 65536
    const size_t off_di   = off_St + 65536;             // 256
    const size_t off_q    = off_di + 256;               // 8192 (qsum; k10 partial after)
    const size_t off_AhT  = off_q + 8192;               // 2097152
    const size_t off_Yp   = off_AhT + 2097152;          // 3145728 scratch region
    const size_t off_C    = off_Yp + 3145728;           // (fused Wf/bfv)
    const size_t off_wts  = off_C + 3145728;            // 665600
    const size_t need_bytes = (off_wts + 665600u) * sizeof(float);

    if (ws_size < need_bytes) {
        k_sentinel<<<8, 64, 0, stream>>>(out, (float)ws_size);
        return;
    }

    float* A    = ws + off_A;
    float* hist = ws + off_hist;
    float* h    = ws + off_h;
    int*   modes= (int*)(ws + off_mode);
    int*   insB = (int*)(ws + off_insB);
    int*   insF = (int*)(ws + off_insF);
    float* St   = ws + off_St;
    float* di   = ws + off_di;
    float* qsum = ws + off_q;
    float* AhT  = ws + off_AhT;
    float* wts  = ws + off_wts;
    // scratch lifetimes (one step):
    //   Y   [0,524288)         kZRH16(t-1)/k1 -> k23h
    //   de1 [1048576,1572864)  k23h -> k45
    //   de2 [1572864,2097152)  k23h -> k45
    float* Y    = ws + off_Yp;
    float* de1  = ws + off_Yp + 1048576;
    float* de2  = ws + off_Yp + 1572864;
    float* Wf   = ws + off_C;            // [3][160][128] = 61440
    float* bfv  = ws + off_C + 61440;    // [3][128] = 384
    float* partial = qsum;   // qsum dead after last kZRH16

    float* Wgf  = wts;
    float* W1f  = wts + 10240;
    float* W2f  = wts + 14336;
    float* Wzf  = wts + 18432;
    float* Wrf  = wts + 22528;
    float* Whf  = wts + 26624;
    float* Wlzf = wts + 30720;
    float* Wlrf = wts + 63488;
    float* Wlhf = wts + 96256;
    float* Wcf  = wts + 129024;

    hipMemsetAsync(ws, 0, zero_end * sizeof(float), stream);

    k_probe_all<<<48, 256, 0, stream>>>(x, ew, Wg, W1, W2, Wz, Wr, Wh, Wlz, Wlr, Wlh, Wc,
                                        insB, insF);
    k_resolve<<<1, 32, 0, stream>>>(insB, insF, modes);
    k_detect_ei<<<1, 64, 0, stream>>>(ei, modes);
    k_cvtall<<<2600, 256, 0, stream>>>(Wg, W1, W2, Wz, Wr, Wh, Wlz, Wlr, Wlh, Wc, modes, wts);
    k_fuse<<<dim3(80, 3), 256, 0, stream>>>(Wzf, Wrf, Whf, Wlzf, Wlrf, Wlhf,
                                            bz, br, bh, blz, blr, blh, Wf, bfv);

    k_scatter<<<NE / 256, 256, 0, stream>>>(ei, ew, A, modes);
    k_roundA<<<NN * NN / 256, 256, 0, stream>>>(A);
    k_di<<<NN / 4, 256, 0, stream>>>(A, di);
    k_St<<<NN * NN / 256, 256, 0, stream>>>(A, di, St);

    for (int t = 0; t < 8; t++) {
        if (t == 0)
            k1_itwg4<<<dim3(NN / 4, BB), 256, 0, stream>>>(x, h, Wgf, Y, 0, modes);
        k23h<<<dim3(NN / 16, BB), 256, 0, stream>>>(St, Y, bg, W1f, W2f, b1, b2,
                                                    de1, de2, qsum, t, modes);
        float inv_cnt = 1.0f / (float)((t + 1 < 3) ? (t + 1) : 3);
        k45<<<dim3(4, 4, BB), 256, 0, stream>>>(de1, de2, hist, AhT, qsum,
                                                t & 1, (t + 1) & 1, inv_cnt);
        kZRH16<<<NN * BB / 16, 256, 0, stream>>>(AhT, qsum, h, Wf, bfv, Wgf, x, Y, t, modes);
    }

    k10a<<<dim3(16, BB), 256, 0, stream>>>(h, Wcf, partial);
    k10b<<<1, 512, 0, stream>>>(partial, bcb, out);
}

// Round 14
// 820.192 us; speedup vs baseline: 1.0138x; 1.0138x over previous
//
#include <hip/hip_runtime.h>
#include <hip/hip_bf16.h>
#include <math.h>

#define BB  32
#define NN  256
#define TT  256
#define WW  32
#define HH  128
#define EMBD 64
#define NCLS 16
#define NE  8192

__device__ __forceinline__ float bf(const __hip_bfloat16* p, int i) {
    return __bfloat162float(p[i]);
}
__device__ __forceinline__ float ld3(const void* p, int i, int m) {
    if (m == 2) return (float)((const double*)p)[i];
    if (m == 1) return ((const float*)p)[i];
    return __bfloat162float(((const __hip_bfloat16*)p)[i]);
}
__device__ __forceinline__ float r16(float x) {
    return __bfloat162float(__float2bfloat16(x));
}
__device__ __forceinline__ float tanh_s(float x) {
    x = fminf(20.0f, fmaxf(-20.0f, x));
    return tanhf(x);
}
__device__ __forceinline__ float sig_s(float x) {
    x = fminf(30.0f, fmaxf(-30.0f, x));
    return 1.0f / (1.0f + expf(-x));
}

// ---------------- guards / dtype detection ----------------

__global__ __launch_bounds__(64) void k_sentinel(float* out, float v) {
    int i = blockIdx.x * 64 + threadIdx.x;
    if (i < BB * NCLS) out[i] = v;
}

__global__ __launch_bounds__(256) void k_probe_all(
        const void* x, const void* ew, const void* Wg, const void* W1, const void* W2,
        const void* Wz, const void* Wr, const void* Wh, const void* Wlz, const void* Wlr,
        const void* Wlh, const void* Wc, int* insB, int* insF) {
    int sec = blockIdx.x >> 2, sub = blockIdx.x & 3;
    const void* p; int nB, idx;
    switch (sec) {
        case 0:  p = x;   nB = 32768; idx = 0;  break;
        case 1:  p = ew;  nB = 8192;  idx = 2;  break;
        case 2:  p = Wg;  nB = 10240; idx = 3;  break;
        case 3:  p = W1;  nB = 4096;  idx = 5;  break;
        case 4:  p = W2;  nB = 4096;  idx = 7;  break;
        case 5:  p = Wz;  nB = 4096;  idx = 9;  break;
        case 6:  p = Wr;  nB = 4096;  idx = 11; break;
        case 7:  p = Wh;  nB = 4096;  idx = 13; break;
        case 8:  p = Wlz; nB = 32768; idx = 15; break;
        case 9:  p = Wlr; nB = 32768; idx = 17; break;
        case 10: p = Wlh; nB = 32768; idx = 19; break;
        default: p = Wc;  nB = 32768; idx = 21; break;
    }
    int nF = nB >> 2;
    const __hip_bfloat16* pb = (const __hip_bfloat16*)p;
    const float* pf = (const float*)p;
    int start = sub * 256 + threadIdx.x;
    for (int i = start; i < nB; i += 1024) {
        float v = __bfloat162float(pb[i]);
        if (!(fabsf(v) < 64.0f)) { insB[idx] = 1; break; }
    }
    for (int i = start; i < nF; i += 1024) {
        float v = pf[i];
        if (!(fabsf(v) < 1e4f)) { insF[idx] = 1; break; }
    }
}

__global__ void k_resolve(const int* insB, const int* insF, int* modes) {
    int i = threadIdx.x;
    if (i < 32 && i != 1)
        modes[i] = insB[i] ? (insF[i] ? 2 : 1) : 0;
}

__global__ __launch_bounds__(64) void k_detect_ei(const int* ei, int* modes) {
    if (threadIdx.x == 0 && blockIdx.x == 0) {
        bool allz = true;
        for (int k = 1; k < 64; k += 2) if (ei[k] != 0) allz = false;
        modes[1] = allz ? 1 : 0;
    }
}

__global__ __launch_bounds__(256) void k_cvtall(const void* Wg, const void* W1, const void* W2,
                                                const void* Wz, const void* Wr, const void* Wh,
                                                const void* Wlz, const void* Wlr, const void* Wlh,
                                                const void* Wc, const int* modes, float* dst) {
    int i = blockIdx.x * 256 + threadIdx.x;
    if (i >= 665600) return;
    float v;
    if      (i < 10240)  v = ld3(Wg,  i,          modes[3]);
    else if (i < 14336)  v = ld3(W1,  i - 10240,  modes[5]);
    else if (i < 18432)  v = ld3(W2,  i - 14336,  modes[7]);
    else if (i < 22528)  v = ld3(Wz,  i - 18432,  modes[9]);
    else if (i < 26624)  v = ld3(Wr,  i - 22528,  modes[11]);
    else if (i < 30720)  v = ld3(Wh,  i - 26624,  modes[13]);
    else if (i < 63488)  v = ld3(Wlz, i - 30720,  modes[15]);
    else if (i < 96256)  v = ld3(Wlr, i - 63488,  modes[17]);
    else if (i < 129024) v = ld3(Wlh, i - 96256,  modes[19]);
    else if (i < 653312) v = ld3(Wc,  i - 129024, modes[21]);
    else {
        int j = i - 653312, w = j / 384, rem = j - w * 384;
        int g = rem >> 7, f = rem & 127;
        const void* Wk = (g == 0) ? Wz : ((g == 1) ? Wr : Wh);
        int mk = (g == 0) ? modes[9] : ((g == 1) ? modes[11] : modes[13]);
        v = ld3(Wk, w * 128 + f, mk);
    }
    dst[i] = v;
}

// k_fuse: build fused GRU weights/biases.
// Wf layout [3][160][128]: rows 0..31 = W_g@Wl_top, rows 32..159 = Wl_bot. bfv [3][128].
__global__ __launch_bounds__(256) void k_fuse(const float* Wzf, const float* Wrf, const float* Whf,
                                              const float* Wlzf, const float* Wlrf, const float* Wlhf,
                                              const __hip_bfloat16* bz, const __hip_bfloat16* br,
                                              const __hip_bfloat16* bh,
                                              const __hip_bfloat16* blz, const __hip_bfloat16* blr,
                                              const __hip_bfloat16* blh,
                                              float* Wf, float* bfv) {
    int g = blockIdx.y;
    const float* Wcv = (g == 0) ? Wzf : ((g == 1) ? Wrf : Whf);
    const float* Wl  = (g == 0) ? Wlzf : ((g == 1) ? Wlrf : Wlhf);
    const __hip_bfloat16* bcv = (g == 0) ? bz : ((g == 1) ? br : bh);
    const __hip_bfloat16* blv = (g == 0) ? blz : ((g == 1) ? blr : blh);
    int idx = blockIdx.x * 256 + threadIdx.x;
    if (idx >= 160 * 128) return;
    int k = idx >> 7, f = idx & 127;
    float v;
    if (k < 32) {
        float acc = 0.f;
        for (int m = 0; m < 128; m++) acc += Wcv[k * 128 + m] * Wl[m * 128 + f];
        v = acc;
    } else {
        v = Wl[(k + 96) * 128 + f];
    }
    Wf[((size_t)g * 160 + k) * 128 + f] = v;
    if (idx < 128) {
        float acc = __bfloat162float(blv[idx]);
        for (int m = 0; m < 128; m++) acc += __bfloat162float(bcv[m]) * Wl[m * 128 + idx];
        bfv[g * 128 + idx] = acc;
    }
}

// ---------------- setup: bf16 static graph ----------------

__global__ __launch_bounds__(256) void k_scatter(const int* ei, const void* ew, float* A,
                                                 const int* modes) {
    int e = blockIdx.x * 256 + threadIdx.x;
    if (e < NE) {
        int s, t;
        if (modes[1]) { s = ei[2 * e]; t = ei[2 * (NE + e)]; }
        else          { s = ei[e];     t = ei[NE + e]; }
        float w = r16(ld3(ew, e, modes[2]));
        if ((unsigned)s < NN && (unsigned)t < NN)
            atomicAdd(&A[s * NN + t], w);
    }
    if (blockIdx.x == 0) atomicAdd(&A[threadIdx.x * NN + threadIdx.x], 1.0f);
}

__global__ __launch_bounds__(256) void k_roundA(float* A) {
    int i = blockIdx.x * 256 + threadIdx.x;
    A[i] = r16(A[i]);
}

__global__ __launch_bounds__(256) void k_di(const float* A, float* di) {
    int wave = threadIdx.x >> 6, lane = threadIdx.x & 63;
    int c = blockIdx.x * 4 + wave;
    float s = 0.f;
    for (int r = lane; r < NN; r += 64) s += A[r * NN + c];
    for (int o = 32; o > 0; o >>= 1) s += __shfl_down(s, o, 64);
    if (lane == 0) {
        float deg = r16(s);
        di[c] = (deg > 0.f) ? r16(1.0f / sqrtf(deg)) : 0.0f;
    }
}

__global__ __launch_bounds__(256) void k_St(const float* A, const float* di, float* St) {
    int idx = blockIdx.x * 256 + threadIdx.x; // idx = c*NN + r
    int c = idx >> 8, r = idx & 255;
    St[idx] = r16(r16(di[r] * A[r * NN + c]) * di[c]);
}

// ---------------- per-step ----------------

// k1: Y = [vt|h] @ Wg. Used only for t=0 (h=0). 4 nodes per 256-thread block.
__global__ __launch_bounds__(256) void k1_itwg4(const void* x, const float* h,
                                                const float* Wgf, float* Y,
                                                int t, const int* modes) {
    __shared__ float vt[4][32];
    __shared__ float hr[4][128];
    int b = blockIdx.y, n0 = blockIdx.x * 4;
    int tid = threadIdx.x;
    int nd = tid >> 6, f = tid & 63;
    if (f < WW) vt[nd][f] = ld3(x, (b * NN + n0 + nd) * TT + t * WW + f, modes[0]);
    size_t hb = (size_t)(b * NN + n0 + nd) * HH;
    hr[nd][f] = h[hb + f];
    hr[nd][f + 64] = h[hb + f + 64];
    __syncthreads();
    float acc = 0.f;
    for (int k = 0; k < WW; k++)  acc += vt[nd][k] * Wgf[k * EMBD + f];
    for (int k = 0; k < HH; k++)  acc += hr[nd][k] * Wgf[(WW + k) * EMBD + f];
    if (t == 0 && modes[0] == 0 && modes[3] == 0) acc = r16(acc);
    Y[(size_t)(b * NN + n0 + nd) * EMBD + f] = acc;
}

// k23h: fused k2+k3 at 2 blocks/CU. 16 c-rows x 64 f per block. grid (16, BB).
__global__ __launch_bounds__(256) void k23h(const float* St, const float* Y,
                                            const __hip_bfloat16* bg,
                                            const float* W1f, const float* W2f,
                                            const __hip_bfloat16* b1, const __hip_bfloat16* b2,
                                            float* de1, float* de2, float* qsum,
                                            int t, const int* modes) {
    __shared__ float AsT[32 * 18];   // St^T slab [k][c], stride 18 (b64-aligned pairs)
    __shared__ float Bs[32 * 68];    // [k][f]
    __shared__ float dfT[64 * 18];   // [f][c]
    int b = blockIdx.y, c0 = blockIdx.x * 16;
    int tid = threadIdx.x;
    if (blockIdx.x == 0) qsum[b * NN + tid] = 0.f;
    int rg = tid >> 5;        // 0-7  -> c-rows rg*2+i
    int cg = tid & 31;        // 0-31 -> f-cols cg*2+j
    const float* Yb = Y + (size_t)b * (NN * EMBD);
    float acc[2][2] = {};
    for (int kb = 0; kb < 256; kb += 32) {
        if (tid < 128) {
            int c = tid >> 3, k4 = (tid & 7) * 4;
            float4 sv = *(const float4*)(St + (size_t)(c0 + c) * 256 + kb + k4);
            AsT[(k4 + 0) * 18 + c] = sv.x;
            AsT[(k4 + 1) * 18 + c] = sv.y;
            AsT[(k4 + 2) * 18 + c] = sv.z;
            AsT[(k4 + 3) * 18 + c] = sv.w;
        }
        {
            int bk = tid >> 3, bn0 = (tid & 7) * 8;
            const float* bp = Yb + (size_t)(kb + bk) * 64 + bn0;
            *(float4*)&Bs[bk * 68 + bn0]     = *(const float4*)bp;
            *(float4*)&Bs[bk * 68 + bn0 + 4] = *(const float4*)(bp + 4);
        }
        __syncthreads();
#pragma unroll 4
        for (int kk = 0; kk < 32; kk++) {
            float2 av = *(const float2*)&AsT[kk * 18 + rg * 2];
            float2 bv = *(const float2*)&Bs[kk * 68 + cg * 2];
            acc[0][0] += av.x * bv.x; acc[0][1] += av.x * bv.y;
            acc[1][0] += av.y * bv.x; acc[1][1] += av.y * bv.y;
        }
        __syncthreads();
    }
    bool rnd = (t == 0 && modes[0] == 0 && modes[3] == 0);
#pragma unroll
    for (int i = 0; i < 2; i++)
#pragma unroll
        for (int j = 0; j < 2; j++) {
            int f = cg * 2 + j;
            float v = (rnd ? r16(acc[i][j]) : acc[i][j]) + bf(bg, f);
            dfT[f * 18 + rg * 2 + i] = v;
        }
    __syncthreads();
    // de1 = tanh(dfT^T @ W1 + b1)
    float a1[2][2] = {};
    for (int kb2 = 0; kb2 < 64; kb2 += 32) {
        int bk = tid >> 3, bn0 = (tid & 7) * 8;
        const float* bp = W1f + (size_t)(kb2 + bk) * 64 + bn0;
        *(float4*)&Bs[bk * 68 + bn0]     = *(const float4*)bp;
        *(float4*)&Bs[bk * 68 + bn0 + 4] = *(const float4*)(bp + 4);
        __syncthreads();
#pragma unroll 4
        for (int kk = 0; kk < 32; kk++) {
            float2 av = *(const float2*)&dfT[(kb2 + kk) * 18 + rg * 2];
            float2 bv = *(const float2*)&Bs[kk * 68 + cg * 2];
            a1[0][0] += av.x * bv.x; a1[0][1] += av.x * bv.y;
            a1[1][0] += av.y * bv.x; a1[1][1] += av.y * bv.y;
        }
        __syncthreads();
    }
#pragma unroll
    for (int i = 0; i < 2; i++) {
        int row = b * NN + c0 + rg * 2 + i;
        float2 o;
        o.x = tanh_s(a1[i][0] + bf(b1, cg * 2 + 0));
        o.y = tanh_s(a1[i][1] + bf(b1, cg * 2 + 1));
        *(float2*)&de1[(size_t)row * 64 + cg * 2] = o;
    }
    // de2 = tanh(dfT^T @ W2 + b2)
    float a2[2][2] = {};
    for (int kb2 = 0; kb2 < 64; kb2 += 32) {
        int bk = tid >> 3, bn0 = (tid & 7) * 8;
        const float* bp = W2f + (size_t)(kb2 + bk) * 64 + bn0;
        *(float4*)&Bs[bk * 68 + bn0]     = *(const float4*)bp;
        *(float4*)&Bs[bk * 68 + bn0 + 4] = *(const float4*)(bp + 4);
        __syncthreads();
#pragma unroll 4
        for (int kk = 0; kk < 32; kk++) {
            float2 av = *(const float2*)&dfT[(kb2 + kk) * 18 + rg * 2];
            float2 bv = *(const float2*)&Bs[kk * 68 + cg * 2];
            a2[0][0] += av.x * bv.x; a2[0][1] += av.x * bv.y;
            a2[1][0] += av.y * bv.x; a2[1][1] += av.y * bv.y;
        }
        __syncthreads();
    }
#pragma unroll
    for (int i = 0; i < 2; i++) {
        int row = b * NN + c0 + rg * 2 + i;
        float2 o;
        o.x = tanh_s(a2[i][0] + bf(b2, cg * 2 + 0));
        o.y = tanh_s(a2[i][1] + bf(b2, cg * 2 + 1));
        *(float2*)&de2[(size_t)row * 64 + cg * 2] = o;
    }
}

// k45: fused M+Et+hist+AhT+qsum. grid (4,4,BB): r0=bx*64, c0=by*64. (R12 form)
__global__ __launch_bounds__(256) void k45(const float* de1, const float* de2,
                                           float* hist, float* AhT, float* qsum,
                                           int slabW, int slabR, float inv_cnt) {
    __shared__ float As[32][68];
    __shared__ float Bs[32][68];
    __shared__ float m2b[64][65];
    __shared__ float qpart[64];
    int b = blockIdx.z, r0 = blockIdx.x * 64, c0 = blockIdx.y * 64;
    int tid = threadIdx.x;
    if (tid < 64) qpart[tid] = 0.f;
    int tn = tid & 15, tm = tid >> 4;
    int am = tid >> 2, ak0 = (tid & 3) * 8;
    int rot = (tid & 3) * 2;
    const float* d1 = de1 + (size_t)b * (NN * EMBD);
    const float* d2 = de2 + (size_t)b * (NN * EMBD);
    // GEMM-A: M2[cl][rl] = de1[c0+cl]·de2[r0+rl]
    float acc2[4][4] = {};
    for (int kb = 0; kb < 64; kb += 32) {
        const float* ap = d1 + (size_t)(c0 + am) * 64 + kb + ak0;
        float4 a0 = *(const float4*)ap;
        float4 a1 = *(const float4*)(ap + 4);
        float av8[8] = {a0.x, a0.y, a0.z, a0.w, a1.x, a1.y, a1.z, a1.w};
#pragma unroll
        for (int jj = 0; jj < 8; jj++) { int j = (jj + rot) & 7; As[ak0 + j][am] = av8[j]; }
        const float* bp = d2 + (size_t)(r0 + am) * 64 + kb + ak0;
        float4 b0 = *(const float4*)bp;
        float4 b1v = *(const float4*)(bp + 4);
        float bv8[8] = {b0.x, b0.y, b0.z, b0.w, b1v.x, b1v.y, b1v.z, b1v.w};
#pragma unroll
        for (int jj = 0; jj < 8; jj++) { int j = (jj + rot) & 7; Bs[ak0 + j][am] = bv8[j]; }
        __syncthreads();
#pragma unroll
        for (int kk = 0; kk < 32; kk++) {
            float4 av = *(const float4*)&As[kk][tm * 4];
            float4 bv = *(const float4*)&Bs[kk][tn * 4];
            float aa[4] = {av.x, av.y, av.z, av.w};
            float bb[4] = {bv.x, bv.y, bv.z, bv.w};
#pragma unroll
            for (int i = 0; i < 4; i++)
#pragma unroll
                for (int j = 0; j < 4; j++) acc2[i][j] += aa[i] * bb[j];
        }
        __syncthreads();
    }
#pragma unroll
    for (int i = 0; i < 4; i++)
#pragma unroll
        for (int j = 0; j < 4; j++) m2b[tm * 4 + i][tn * 4 + j] = acc2[i][j];
    // GEMM-B: M1[rl][cl] = de1[r0+rl]·de2[c0+cl]
    float acc1[4][4] = {};
    for (int kb = 0; kb < 64; kb += 32) {
        const float* ap = d1 + (size_t)(r0 + am) * 64 + kb + ak0;
        float4 a0 = *(const float4*)ap;
        float4 a1 = *(const float4*)(ap + 4);
        float av8[8] = {a0.x, a0.y, a0.z, a0.w, a1.x, a1.y, a1.z, a1.w};
#pragma unroll
        for (int jj = 0; jj < 8; jj++) { int j = (jj + rot) & 7; As[ak0 + j][am] = av8[j]; }
        const float* bp = d2 + (size_t)(c0 + am) * 64 + kb + ak0;
        float4 b0 = *(const float4*)bp;
        float4 b1v = *(const float4*)(bp + 4);
        float bv8[8] = {b0.x, b0.y, b0.z, b0.w, b1v.x, b1v.y, b1v.z, b1v.w};
#pragma unroll
        for (int jj = 0; jj < 8; jj++) { int j = (jj + rot) & 7; Bs[ak0 + j][am] = bv8[j]; }
        __syncthreads();
#pragma unroll
        for (int kk = 0; kk < 32; kk++) {
            float4 av = *(const float4*)&As[kk][tm * 4];
            float4 bv = *(const float4*)&Bs[kk][tn * 4];
            float aa[4] = {av.x, av.y, av.z, av.w};
            float bb[4] = {bv.x, bv.y, bv.z, bv.w};
#pragma unroll
            for (int i = 0; i < 4; i++)
#pragma unroll
                for (int j = 0; j < 4; j++) acc1[i][j] += aa[i] * bb[j];
        }
        __syncthreads();
    }
    // Et + hist roll + ad; hist I/O float4 along c
    size_t NB = (size_t)BB * NN * NN;
    float* hsW = hist + (size_t)slabW * NB;
    const float* hsR = hist + (size_t)slabR * NB;
    float ad[4][4];
#pragma unroll
    for (int i = 0; i < 4; i++) {
        int r = r0 + tm * 4 + i;
        size_t o = ((size_t)(b * NN + r)) * NN + c0 + tn * 4;
        float4 e2v = *(const float4*)&hsW[o];
        float4 e1v = *(const float4*)&hsR[o];
        float e2a[4] = {e2v.x, e2v.y, e2v.z, e2v.w};
        float e1a[4] = {e1v.x, e1v.y, e1v.z, e1v.w};
        float4 ew4;
        float eo[4];
#pragma unroll
        for (int j = 0; j < 4; j++) {
            int c = c0 + tn * 4 + j;
            float e = tanh_s(acc1[i][j] - m2b[tn * 4 + j][tm * 4 + i]);
            e = e > 0.f ? e : 0.f;
            eo[j] = e;
            float mt = (e + e1a[j] + e2a[j]) * inv_cnt;
            float adv = (mt > 1e-8f) ? mt : 0.f;
            if (r == c) adv += 1.f;
            ad[i][j] = adv;
        }
        ew4.x = eo[0]; ew4.y = eo[1]; ew4.z = eo[2]; ew4.w = eo[3];
        *(float4*)&hsW[o] = ew4;
    }
    // qsum partials: column sums over this tile's rows
#pragma unroll
    for (int j = 0; j < 4; j++) {
        float cs = ad[0][j] + ad[1][j] + ad[2][j] + ad[3][j];
        atomicAdd(&qpart[tn * 4 + j], cs);
    }
    // stage ad transposed for coalesced AhT write (reuse m2b after all reads)
    __syncthreads();
#pragma unroll
    for (int i = 0; i < 4; i++)
#pragma unroll
        for (int j = 0; j < 4; j++) m2b[tn * 4 + j][tm * 4 + i] = ad[i][j];
    __syncthreads();
#pragma unroll
    for (int kk = 0; kk < 4; kk++) {
        int e = tid + kk * 256;
        int cl = e >> 4, q4 = e & 15;
        float4 o;
        o.x = m2b[cl][q4 * 4 + 0]; o.y = m2b[cl][q4 * 4 + 1];
        o.z = m2b[cl][q4 * 4 + 2]; o.w = m2b[cl][q4 * 4 + 3];
        *(float4*)&AhT[((size_t)(b * NN + c0 + cl)) * NN + r0 + q4 * 4] = o;
    }
    if (tid < 64) atomicAdd(&qsum[b * NN + c0 + tid], qpart[tid]);
}

// kZRH16: fused G + GRU + next-step Y. grid 512: 16 rows/block (2 blocks/CU).
// R14: Bs+zbuf merged into one pool so the Y phase can preload ALL of Wgf
// (160x64 = 10240 floats) and run its 160-k loop with ZERO barriers.
// Gate role-split (R13) retained. All per-element k-orders unchanged ->
// bit-identical output.
__global__ __launch_bounds__(256) void kZRH16(const float* AhT, const float* qsum, float* h,
                                              const float* Wf, const float* bfv,
                                              const float* Wgf, const void* x, float* Y,
                                              int t, const int* modes) {
    __shared__ float qrow[256];
    __shared__ float As[160 * 20];   // [k][row], 16 rows, stride 20
    __shared__ float pool[10496];    // Bs[0..8448) + zbuf[8448..10496); Y: Wgf[0..10240)
    float* Bs   = pool;
    float* zbuf = pool + 8448;       // [16][128]
    int r0 = blockIdx.x * 16;        // global row (b*NN + n)
    int b  = r0 >> 8;
    int tid = threadIdx.x;
    int m0 = modes[0];
    // stage h^T: h[r0+r][c] -> As[(32+c)*20 + r]
#pragma unroll
    for (int u = 0; u < 2; u++) {
        int e = tid * 2 + u;
        int r = e >> 5, c4 = (e & 31) * 4;
        float4 hv = *(const float4*)&h[(size_t)(r0 + r) * 128 + c4];
        As[(32 + c4 + 0) * 20 + r] = hv.x;
        As[(32 + c4 + 1) * 20 + r] = hv.y;
        As[(32 + c4 + 2) * 20 + r] = hv.z;
        As[(32 + c4 + 3) * 20 + r] = hv.w;
    }
    qrow[tid] = 1.0f / sqrtf(fmaxf(qsum[b * NN + tid], 1e-12f));
    __syncthreads();

    // ---- phase 0: G into As G-region ----
    {
        float* vtq = Bs;            // [32 w][132 r]
        float* Ah  = Bs + 4224;     // [16][132]
        float gacc[2] = {0.f, 0.f};
        int gi = tid & 15, gw = (tid >> 4) * 2;
        for (int half = 0; half < 2; half++) {
            int wv = tid & 31, rb = tid >> 5;
#pragma unroll
            for (int k = 0; k < 16; k++) {
                int rl = rb + 8 * k;
                int rg = half * 128 + rl;
                vtq[wv * 132 + rl] = qrow[rg] * ld3(x, (b * NN + rg) * TT + t * WW + wv, m0);
            }
            {
                int i = tid >> 4, c8 = (tid & 15) * 8;
                const float* ap = AhT + (size_t)(r0 + i) * NN + half * 128 + c8;
                *(float4*)&Ah[i * 132 + c8]     = *(const float4*)ap;
                *(float4*)&Ah[i * 132 + c8 + 4] = *(const float4*)(ap + 4);
            }
            __syncthreads();
            for (int r = 0; r < 128; r += 4) {
                float4 a  = *(const float4*)&Ah[gi * 132 + r];
                float4 v0 = *(const float4*)&vtq[gw * 132 + r];
                float4 v1 = *(const float4*)&vtq[(gw + 1) * 132 + r];
                gacc[0] += a.x * v0.x;
                gacc[1] += a.x * v1.x;
                gacc[0] += a.y * v0.y;
                gacc[1] += a.y * v1.y;
                gacc[0] += a.z * v0.z;
                gacc[1] += a.z * v1.z;
                gacc[0] += a.w * v0.w;
                gacc[1] += a.w * v1.w;
            }
            __syncthreads();
        }
        float qc = qrow[(r0 & 255) + gi];
        As[gw * 20 + gi]       = qc * gacc[0];
        As[(gw + 1) * 20 + gi] = qc * gacc[1];
        // gates stage Bs then sync before reading As G-region
    }

    // ---- gates: role-split. tid<128 -> Z, tid>=128 -> R. 4r x 4c tiles. ----
    {
        int gsel = tid >> 7;                 // 0 = Z, 1 = R
        int rt = (tid >> 5) & 3;             // rows rt*4+i
        int ct = tid & 31;                   // cols ct*4+j
        const float* W0 = Wf;
        const float* W1 = Wf + (size_t)(160 * 128);
        float accG[4][4] = {};
        for (int kb = 0; kb < 160; kb += 32) {
#pragma unroll
            for (int u = 0; u < 4; u++) {
                int e = tid + u * 256;
                int kk = e >> 5, c4 = (e & 31) * 4;
                *(float4*)&Bs[kk * 128 + c4]        = *(const float4*)&W0[(size_t)(kb + kk) * 128 + c4];
                *(float4*)&Bs[4096 + kk * 128 + c4] = *(const float4*)&W1[(size_t)(kb + kk) * 128 + c4];
            }
            __syncthreads();
            const float* Bp = Bs + gsel * 4096;
#pragma unroll 4
            for (int kk = 0; kk < 32; kk++) {
                float4 av = *(const float4*)&As[(kb + kk) * 20 + rt * 4];
                float4 bv = *(const float4*)&Bp[kk * 128 + ct * 4];
                accG[0][0] += av.x * bv.x; accG[0][1] += av.x * bv.y;
                accG[0][2] += av.x * bv.z; accG[0][3] += av.x * bv.w;
                accG[1][0] += av.y * bv.x; accG[1][1] += av.y * bv.y;
                accG[1][2] += av.y * bv.z; accG[1][3] += av.y * bv.w;
                accG[2][0] += av.z * bv.x; accG[2][1] += av.z * bv.y;
                accG[2][2] += av.z * bv.z; accG[2][3] += av.z * bv.w;
                accG[3][0] += av.w * bv.x; accG[3][1] += av.w * bv.y;
                accG[3][2] += av.w * bv.z; accG[3][3] += av.w * bv.w;
            }
            __syncthreads();
        }
        if (gsel == 0) {
            // Z -> zbuf
#pragma unroll
            for (int i = 0; i < 4; i++)
#pragma unroll
                for (int j = 0; j < 4; j++)
                    zbuf[(rt * 4 + i) * 128 + ct * 4 + j] =
                        sig_s(accG[i][j] + bfv[ct * 4 + j]);
        } else {
            // R -> hR in place (each slot owned by exactly one thread)
#pragma unroll
            for (int i = 0; i < 4; i++)
#pragma unroll
                for (int j = 0; j < 4; j++) {
                    float rv = sig_s(accG[i][j] + bfv[128 + ct * 4 + j]);
                    int slot = (32 + ct * 4 + j) * 20 + rt * 4 + i;
                    As[slot] = As[slot] * rv;
                }
        }
        // next phase's staging + sync orders these writes before any read
    }

    int rg = tid >> 5, cg = tid & 31;   // 2r x 4c for Ht / h-update
    // ---- Ht GEMM over [G|hR] (panel 0 of Bs) ----
    float acc[2][4] = {};
    {
        const float* Wgp = Wf + (size_t)2 * (160 * 128);
        for (int kb = 0; kb < 160; kb += 32) {
#pragma unroll
            for (int u = 0; u < 4; u++) {
                int e = tid + u * 256;
                int kk = e >> 5, c4 = (e & 31) * 4;
                *(float4*)&Bs[kk * 128 + c4] = *(const float4*)&Wgp[(size_t)(kb + kk) * 128 + c4];
            }
            __syncthreads();
#pragma unroll 4
            for (int kk = 0; kk < 32; kk++) {
                float2 av = *(const float2*)&As[(kb + kk) * 20 + rg * 2];
                float4 bv = *(const float4*)&Bs[kk * 128 + cg * 4];
                acc[0][0] += av.x * bv.x; acc[0][1] += av.x * bv.y;
                acc[0][2] += av.x * bv.z; acc[0][3] += av.x * bv.w;
                acc[1][0] += av.y * bv.x; acc[1][1] += av.y * bv.y;
                acc[1][2] += av.y * bv.z; acc[1][3] += av.y * bv.w;
            }
            __syncthreads();
        }
    }
    // ---- h-update; write h global + refresh As h-region with h_new ----
#pragma unroll
    for (int i = 0; i < 2; i++) {
        int row = r0 + rg * 2 + i;
        size_t o = (size_t)row * 128 + cg * 4;
        float4 hv = *(const float4*)&h[o];       // h_old (global still intact)
        float4 zq = *(const float4*)&zbuf[(rg * 2 + i) * 128 + cg * 4];
        float4 r;
        r.x = zq.x * hv.x + (1.0f - zq.x) * tanh_s(acc[i][0] + bfv[256 + cg * 4 + 0]);
        r.y = zq.y * hv.y + (1.0f - zq.y) * tanh_s(acc[i][1] + bfv[256 + cg * 4 + 1]);
        r.z = zq.z * hv.z + (1.0f - zq.z) * tanh_s(acc[i][2] + bfv[256 + cg * 4 + 2]);
        r.w = zq.w * hv.w + (1.0f - zq.w) * tanh_s(acc[i][3] + bfv[256 + cg * 4 + 3]);
        *(float4*)&h[o] = r;
        As[(32 + cg * 4 + 0) * 20 + rg * 2 + i] = r.x;
        As[(32 + cg * 4 + 1) * 20 + rg * 2 + i] = r.y;
        As[(32 + cg * 4 + 2) * 20 + rg * 2 + i] = r.z;
        As[(32 + cg * 4 + 3) * 20 + rg * 2 + i] = r.w;
    }
    // ---- next-step Y = [vt(t+1)|h_new] @ Wgf (full Wgf resident; no inner barriers) ----
    if (t < 7) {
        __syncthreads();   // zbuf reads + As h-writes complete before pool overwrite
        // stage vt2^T into the dead G-region
#pragma unroll
        for (int u = 0; u < 2; u++) {
            int e = tid * 2 + u;
            int r = e >> 5, w = e & 31;
            As[w * 20 + r] = ld3(x, (r0 + r) * TT + (t + 1) * WW + w, m0);
        }
        // preload ALL of Wgf: 10240 floats = 2560 float4, 10 per thread
#pragma unroll
        for (int u = 0; u < 10; u++) {
            int e = tid + u * 256;
            *(float4*)&pool[e * 4] = *(const float4*)&Wgf[(size_t)e * 4];
        }
        __syncthreads();
        int yr = tid >> 4, yc4 = (tid & 15) * 4;
        float yacc[4] = {0.f, 0.f, 0.f, 0.f};
#pragma unroll 8
        for (int k = 0; k < 160; k++) {
            float a = As[k * 20 + yr];
            float4 bv = *(const float4*)&pool[k * 64 + yc4];
            yacc[0] += a * bv.x; yacc[1] += a * bv.y;
            yacc[2] += a * bv.z; yacc[3] += a * bv.w;
        }
        *(float4*)&Y[(size_t)(r0 + yr) * 64 + yc4] =
            make_float4(yacc[0], yacc[1], yacc[2], yacc[3]);
    }
}

__global__ __launch_bounds__(256) void k10a(const float* h, const float* Wcf, float* partial) {
    __shared__ float red[16][17];
    int chunk = blockIdx.x, b = blockIdx.y;
    int c = threadIdx.x & 15, isub = threadIdx.x >> 4;
    const float* hb = h + (size_t)b * (NN * HH);
    int i0 = chunk * 2048;
    float acc = 0.f;
    for (int s = 0; s < 128; s++) {
        int i = i0 + isub + 16 * s;
        acc += hb[i] * Wcf[(size_t)i * NCLS + c];
    }
    red[isub][c] = acc;
    __syncthreads();
    for (int st = 8; st > 0; st >>= 1) {
        if (isub < st) red[isub][c] += red[isub + st][c];
        __syncthreads();
    }
    if (isub == 0) partial[((size_t)(b * NCLS + c)) * 16 + chunk] = red[0][c];
}

__global__ __launch_bounds__(512) void k10b(const float* partial, const __hip_bfloat16* bcb,
                                            float* out) {
    int tid = threadIdx.x;
    if (tid < BB * NCLS) {
        int c = tid & 15;
        float s = 0.f;
        for (int k = 0; k < 16; k++) s += partial[(size_t)tid * 16 + k];
        out[tid] = s + bf(bcb, c);
    }
}

// ---------------- launch ----------------

extern "C" void kernel_launch(void* const* d_in, const int* in_sizes, int n_in,
                              void* d_out, int out_size, void* d_ws, size_t ws_size,
                              hipStream_t stream) {
    float* out = (float*)d_out;

    static const int exp_sizes[23] = {2097152, 16384, 8192, 10240, 64, 4096, 64, 4096, 64,
                                      4096, 128, 4096, 128, 4096, 128, 32768, 128, 32768, 128,
                                      32768, 128, 524288, 16};
    if (n_in != 23) { k_sentinel<<<8, 64, 0, stream>>>(out, 4444.0f); return; }
    for (int i = 0; i < 23; i++) {
        if (in_sizes[i] != exp_sizes[i]) {
            k_sentinel<<<8, 64, 0, stream>>>(out, (float)(4000 + i));
            return;
        }
    }

    const void* x   = d_in[0];
    const int*  ei  = (const int*)d_in[1];
    const void* ew  = d_in[2];
    const void* Wg  = d_in[3];
    const __hip_bfloat16* bg  = (const __hip_bfloat16*)d_in[4];
    const void* W1  = d_in[5];
    const __hip_bfloat16* b1  = (const __hip_bfloat16*)d_in[6];
    const void* W2  = d_in[7];
    const __hip_bfloat16* b2  = (const __hip_bfloat16*)d_in[8];
    const void* Wz  = d_in[9];
    const __hip_bfloat16* bz  = (const __hip_bfloat16*)d_in[10];
    const void* Wr  = d_in[11];
    const __hip_bfloat16* br  = (const __hip_bfloat16*)d_in[12];
    const void* Wh  = d_in[13];
    const __hip_bfloat16* bh  = (const __hip_bfloat16*)d_in[14];
    const void* Wlz = d_in[15];
    const __hip_bfloat16* blz = (const __hip_bfloat16*)d_in[16];
    const void* Wlr = d_in[17];
    const __hip_bfloat16* blr = (const __hip_bfloat16*)d_in[18];
    const void* Wlh = d_in[19];
    const __hip_bfloat16* blh = (const __hip_bfloat16*)d_in[20];
    const void* Wc  = d_in[21];
    const __hip_bfloat16* bcb = (const __hip_bfloat16*)d_in[22];

    float* ws = (float*)d_ws;
    const size_t off_A    = 0;                          // 65536
    const size_t off_hist = off_A + 65536;              // 2*2097152
    const size_t off_h    = off_hist + 2u * 2097152;    // 1048576
    const size_t off_flag = off_h + 1048576;            // 16
    const size_t off_mode = off_flag + 16;              // 32
    const size_t off_insB = off_mode + 32;              // 32
    const size_t off_insF = off_insB + 32;              // 32
    const size_t zero_end = off_insF + 32;
    const size_t off_St   = zero_end;                   // 65536
    const size_t off_di   = off_St + 65536;             // 256
    const size_t off_q    = off_di + 256;               // 8192 (qsum; k10 partial after)
    const size_t off_AhT  = off_q + 8192;               // 2097152
    const size_t off_Yp   = off_AhT + 2097152;          // 3145728 scratch region
    const size_t off_C    = off_Yp + 3145728;           // (fused Wf/bfv)
    const size_t off_wts  = off_C + 3145728;            // 665600
    const size_t need_bytes = (off_wts + 665600u) * sizeof(float);

    if (ws_size < need_bytes) {
        k_sentinel<<<8, 64, 0, stream>>>(out, (float)ws_size);
        return;
    }

    float* A    = ws + off_A;
    float* hist = ws + off_hist;
    float* h    = ws + off_h;
    int*   modes= (int*)(ws + off_mode);
    int*   insB = (int*)(ws + off_insB);
    int*   insF = (int*)(ws + off_insF);
    float* St   = ws + off_St;
    float* di   = ws + off_di;
    float* qsum = ws + off_q;
    float* AhT  = ws + off_AhT;
    float* wts  = ws + off_wts;
    // scratch lifetimes (one step):
    //   Y   [0,524288)         kZRH16(t-1)/k1 -> k23h
    //   de1 [1048576,1572864)  k23h -> k45
    //   de2 [1572864,2097152)  k23h -> k45
    float* Y    = ws + off_Yp;
    float* de1  = ws + off_Yp + 1048576;
    float* de2  = ws + off_Yp + 1572864;
    float* Wf   = ws + off_C;            // [3][160][128] = 61440
    float* bfv  = ws + off_C + 61440;    // [3][128] = 384
    float* partial = qsum;   // qsum dead after last kZRH16

    float* Wgf  = wts;
    float* W1f  = wts + 10240;
    float* W2f  = wts + 14336;
    float* Wzf  = wts + 18432;
    float* Wrf  = wts + 22528;
    float* Whf  = wts + 26624;
    float* Wlzf = wts + 30720;
    float* Wlrf = wts + 63488;
    float* Wlhf = wts + 96256;
    float* Wcf  = wts + 129024;

    hipMemsetAsync(ws, 0, zero_end * sizeof(float), stream);

    k_probe_all<<<48, 256, 0, stream>>>(x, ew, Wg, W1, W2, Wz, Wr, Wh, Wlz, Wlr, Wlh, Wc,
                                        insB, insF);
    k_resolve<<<1, 32, 0, stream>>>(insB, insF, modes);
    k_detect_ei<<<1, 64, 0, stream>>>(ei, modes);
    k_cvtall<<<2600, 256, 0, stream>>>(Wg, W1, W2, Wz, Wr, Wh, Wlz, Wlr, Wlh, Wc, modes, wts);
    k_fuse<<<dim3(80, 3), 256, 0, stream>>>(Wzf, Wrf, Whf, Wlzf, Wlrf, Wlhf,
                                            bz, br, bh, blz, blr, blh, Wf, bfv);

    k_scatter<<<NE / 256, 256, 0, stream>>>(ei, ew, A, modes);
    k_roundA<<<NN * NN / 256, 256, 0, stream>>>(A);
    k_di<<<NN / 4, 256, 0, stream>>>(A, di);
    k_St<<<NN * NN / 256, 256, 0, stream>>>(A, di, St);

    for (int t = 0; t < 8; t++) {
        if (t == 0)
            k1_itwg4<<<dim3(NN / 4, BB), 256, 0, stream>>>(x, h, Wgf, Y, 0, modes);
        k23h<<<dim3(NN / 16, BB), 256, 0, stream>>>(St, Y, bg, W1f, W2f, b1, b2,
                                                    de1, de2, qsum, t, modes);
        float inv_cnt = 1.0f / (float)((t + 1 < 3) ? (t + 1) : 3);
        k45<<<dim3(4, 4, BB), 256, 0, stream>>>(de1, de2, hist, AhT, qsum,
                                                t & 1, (t + 1) & 1, inv_cnt);
        kZRH16<<<NN * BB / 16, 256, 0, stream>>>(AhT, qsum, h, Wf, bfv, Wgf, x, Y, t, modes);
    }

    k10a<<<dim3(16, BB), 256, 0, stream>>>(h, Wcf, partial);
    k10b<<<1, 512, 0, stream>>>(partial, bcb, out);
}

// Round 15
// 803.664 us; speedup vs baseline: 1.0347x; 1.0206x over previous
//
#include <hip/hip_runtime.h>
#include <hip/hip_bf16.h>
#include <math.h>

#define BB  32
#define NN  256
#define TT  256
#define WW  32
#define HH  128
#define EMBD 64
#define NCLS 16
#define NE  8192

__device__ __forceinline__ float bf(const __hip_bfloat16* p, int i) {
    return __bfloat162float(p[i]);
}
__device__ __forceinline__ float ld3(const void* p, int i, int m) {
    if (m == 2) return (float)((const double*)p)[i];
    if (m == 1) return ((const float*)p)[i];
    return __bfloat162float(((const __hip_bfloat16*)p)[i]);
}
__device__ __forceinline__ float r16(float x) {
    return __bfloat162float(__float2bfloat16(x));
}
__device__ __forceinline__ float tanh_s(float x) {
    x = fminf(20.0f, fmaxf(-20.0f, x));
    return tanhf(x);
}
__device__ __forceinline__ float sig_s(float x) {
    x = fminf(30.0f, fmaxf(-30.0f, x));
    return 1.0f / (1.0f + expf(-x));
}

// ---------------- guards / dtype detection ----------------

__global__ __launch_bounds__(64) void k_sentinel(float* out, float v) {
    int i = blockIdx.x * 64 + threadIdx.x;
    if (i < BB * NCLS) out[i] = v;
}

__global__ __launch_bounds__(256) void k_probe_all(
        const void* x, const void* ew, const void* Wg, const void* W1, const void* W2,
        const void* Wz, const void* Wr, const void* Wh, const void* Wlz, const void* Wlr,
        const void* Wlh, const void* Wc, int* insB, int* insF) {
    int sec = blockIdx.x >> 2, sub = blockIdx.x & 3;
    const void* p; int nB, idx;
    switch (sec) {
        case 0:  p = x;   nB = 32768; idx = 0;  break;
        case 1:  p = ew;  nB = 8192;  idx = 2;  break;
        case 2:  p = Wg;  nB = 10240; idx = 3;  break;
        case 3:  p = W1;  nB = 4096;  idx = 5;  break;
        case 4:  p = W2;  nB = 4096;  idx = 7;  break;
        case 5:  p = Wz;  nB = 4096;  idx = 9;  break;
        case 6:  p = Wr;  nB = 4096;  idx = 11; break;
        case 7:  p = Wh;  nB = 4096;  idx = 13; break;
        case 8:  p = Wlz; nB = 32768; idx = 15; break;
        case 9:  p = Wlr; nB = 32768; idx = 17; break;
        case 10: p = Wlh; nB = 32768; idx = 19; break;
        default: p = Wc;  nB = 32768; idx = 21; break;
    }
    int nF = nB >> 2;
    const __hip_bfloat16* pb = (const __hip_bfloat16*)p;
    const float* pf = (const float*)p;
    int start = sub * 256 + threadIdx.x;
    for (int i = start; i < nB; i += 1024) {
        float v = __bfloat162float(pb[i]);
        if (!(fabsf(v) < 64.0f)) { insB[idx] = 1; break; }
    }
    for (int i = start; i < nF; i += 1024) {
        float v = pf[i];
        if (!(fabsf(v) < 1e4f)) { insF[idx] = 1; break; }
    }
}

__global__ void k_resolve(const int* insB, const int* insF, int* modes) {
    int i = threadIdx.x;
    if (i < 32 && i != 1)
        modes[i] = insB[i] ? (insF[i] ? 2 : 1) : 0;
}

__global__ __launch_bounds__(64) void k_detect_ei(const int* ei, int* modes) {
    if (threadIdx.x == 0 && blockIdx.x == 0) {
        bool allz = true;
        for (int k = 1; k < 64; k += 2) if (ei[k] != 0) allz = false;
        modes[1] = allz ? 1 : 0;
    }
}

__global__ __launch_bounds__(256) void k_cvtall(const void* Wg, const void* W1, const void* W2,
                                                const void* Wz, const void* Wr, const void* Wh,
                                                const void* Wlz, const void* Wlr, const void* Wlh,
                                                const void* Wc, const int* modes, float* dst) {
    int i = blockIdx.x * 256 + threadIdx.x;
    if (i >= 665600) return;
    float v;
    if      (i < 10240)  v = ld3(Wg,  i,          modes[3]);
    else if (i < 14336)  v = ld3(W1,  i - 10240,  modes[5]);
    else if (i < 18432)  v = ld3(W2,  i - 14336,  modes[7]);
    else if (i < 22528)  v = ld3(Wz,  i - 18432,  modes[9]);
    else if (i < 26624)  v = ld3(Wr,  i - 22528,  modes[11]);
    else if (i < 30720)  v = ld3(Wh,  i - 26624,  modes[13]);
    else if (i < 63488)  v = ld3(Wlz, i - 30720,  modes[15]);
    else if (i < 96256)  v = ld3(Wlr, i - 63488,  modes[17]);
    else if (i < 129024) v = ld3(Wlh, i - 96256,  modes[19]);
    else if (i < 653312) v = ld3(Wc,  i - 129024, modes[21]);
    else {
        int j = i - 653312, w = j / 384, rem = j - w * 384;
        int g = rem >> 7, f = rem & 127;
        const void* Wk = (g == 0) ? Wz : ((g == 1) ? Wr : Wh);
        int mk = (g == 0) ? modes[9] : ((g == 1) ? modes[11] : modes[13]);
        v = ld3(Wk, w * 128 + f, mk);
    }
    dst[i] = v;
}

// k_fuse: build fused GRU weights/biases.
// Wf layout [3][160][128]: rows 0..31 = W_g@Wl_top, rows 32..159 = Wl_bot. bfv [3][128].
__global__ __launch_bounds__(256) void k_fuse(const float* Wzf, const float* Wrf, const float* Whf,
                                              const float* Wlzf, const float* Wlrf, const float* Wlhf,
                                              const __hip_bfloat16* bz, const __hip_bfloat16* br,
                                              const __hip_bfloat16* bh,
                                              const __hip_bfloat16* blz, const __hip_bfloat16* blr,
                                              const __hip_bfloat16* blh,
                                              float* Wf, float* bfv) {
    int g = blockIdx.y;
    const float* Wcv = (g == 0) ? Wzf : ((g == 1) ? Wrf : Whf);
    const float* Wl  = (g == 0) ? Wlzf : ((g == 1) ? Wlrf : Wlhf);
    const __hip_bfloat16* bcv = (g == 0) ? bz : ((g == 1) ? br : bh);
    const __hip_bfloat16* blv = (g == 0) ? blz : ((g == 1) ? blr : blh);
    int idx = blockIdx.x * 256 + threadIdx.x;
    if (idx >= 160 * 128) return;
    int k = idx >> 7, f = idx & 127;
    float v;
    if (k < 32) {
        float acc = 0.f;
        for (int m = 0; m < 128; m++) acc += Wcv[k * 128 + m] * Wl[m * 128 + f];
        v = acc;
    } else {
        v = Wl[(k + 96) * 128 + f];
    }
    Wf[((size_t)g * 160 + k) * 128 + f] = v;
    if (idx < 128) {
        float acc = __bfloat162float(blv[idx]);
        for (int m = 0; m < 128; m++) acc += __bfloat162float(bcv[m]) * Wl[m * 128 + idx];
        bfv[g * 128 + idx] = acc;
    }
}

// ---------------- setup: bf16 static graph ----------------

__global__ __launch_bounds__(256) void k_scatter(const int* ei, const void* ew, float* A,
                                                 const int* modes) {
    int e = blockIdx.x * 256 + threadIdx.x;
    if (e < NE) {
        int s, t;
        if (modes[1]) { s = ei[2 * e]; t = ei[2 * (NE + e)]; }
        else          { s = ei[e];     t = ei[NE + e]; }
        float w = r16(ld3(ew, e, modes[2]));
        if ((unsigned)s < NN && (unsigned)t < NN)
            atomicAdd(&A[s * NN + t], w);
    }
    if (blockIdx.x == 0) atomicAdd(&A[threadIdx.x * NN + threadIdx.x], 1.0f);
}

__global__ __launch_bounds__(256) void k_roundA(float* A) {
    int i = blockIdx.x * 256 + threadIdx.x;
    A[i] = r16(A[i]);
}

__global__ __launch_bounds__(256) void k_di(const float* A, float* di) {
    int wave = threadIdx.x >> 6, lane = threadIdx.x & 63;
    int c = blockIdx.x * 4 + wave;
    float s = 0.f;
    for (int r = lane; r < NN; r += 64) s += A[r * NN + c];
    for (int o = 32; o > 0; o >>= 1) s += __shfl_down(s, o, 64);
    if (lane == 0) {
        float deg = r16(s);
        di[c] = (deg > 0.f) ? r16(1.0f / sqrtf(deg)) : 0.0f;
    }
}

__global__ __launch_bounds__(256) void k_St(const float* A, const float* di, float* St) {
    int idx = blockIdx.x * 256 + threadIdx.x; // idx = c*NN + r
    int c = idx >> 8, r = idx & 255;
    St[idx] = r16(r16(di[r] * A[r * NN + c]) * di[c]);
}

// ---------------- per-step ----------------

// k1: Y = [vt|h] @ Wg. Used only for t=0 (h=0). 4 nodes per 256-thread block.
__global__ __launch_bounds__(256) void k1_itwg4(const void* x, const float* h,
                                                const float* Wgf, float* Y,
                                                int t, const int* modes) {
    __shared__ float vt[4][32];
    __shared__ float hr[4][128];
    int b = blockIdx.y, n0 = blockIdx.x * 4;
    int tid = threadIdx.x;
    int nd = tid >> 6, f = tid & 63;
    if (f < WW) vt[nd][f] = ld3(x, (b * NN + n0 + nd) * TT + t * WW + f, modes[0]);
    size_t hb = (size_t)(b * NN + n0 + nd) * HH;
    hr[nd][f] = h[hb + f];
    hr[nd][f + 64] = h[hb + f + 64];
    __syncthreads();
    float acc = 0.f;
    for (int k = 0; k < WW; k++)  acc += vt[nd][k] * Wgf[k * EMBD + f];
    for (int k = 0; k < HH; k++)  acc += hr[nd][k] * Wgf[(WW + k) * EMBD + f];
    if (t == 0 && modes[0] == 0 && modes[3] == 0) acc = r16(acc);
    Y[(size_t)(b * NN + n0 + nd) * EMBD + f] = acc;
}

// k23h: fused k2+k3 at 2 blocks/CU. 16 c-rows x 64 f per block. grid (16, BB).
// R15: de1/de2 GEMMs merged into ONE k-loop with both W1/W2 panels staged
// (same pattern as kZRH16's R9 gate merge): dfT A-reads halve, barrier pairs
// halve. Per-output k-order unchanged -> bit-identical.
__global__ __launch_bounds__(256) void k23h(const float* St, const float* Y,
                                            const __hip_bfloat16* bg,
                                            const float* W1f, const float* W2f,
                                            const __hip_bfloat16* b1, const __hip_bfloat16* b2,
                                            float* de1, float* de2, float* qsum,
                                            int t, const int* modes) {
    __shared__ float AsT[32 * 18];   // St^T slab [k][c], stride 18 (b64-aligned pairs)
    __shared__ float Bs[2 * 32 * 68]; // two [k][f] panels
    __shared__ float dfT[64 * 18];   // [f][c]
    int b = blockIdx.y, c0 = blockIdx.x * 16;
    int tid = threadIdx.x;
    if (blockIdx.x == 0) qsum[b * NN + tid] = 0.f;
    int rg = tid >> 5;        // 0-7  -> c-rows rg*2+i
    int cg = tid & 31;        // 0-31 -> f-cols cg*2+j
    const float* Yb = Y + (size_t)b * (NN * EMBD);
    float acc[2][2] = {};
    for (int kb = 0; kb < 256; kb += 32) {
        if (tid < 128) {
            int c = tid >> 3, k4 = (tid & 7) * 4;
            float4 sv = *(const float4*)(St + (size_t)(c0 + c) * 256 + kb + k4);
            AsT[(k4 + 0) * 18 + c] = sv.x;
            AsT[(k4 + 1) * 18 + c] = sv.y;
            AsT[(k4 + 2) * 18 + c] = sv.z;
            AsT[(k4 + 3) * 18 + c] = sv.w;
        }
        {
            int bk = tid >> 3, bn0 = (tid & 7) * 8;
            const float* bp = Yb + (size_t)(kb + bk) * 64 + bn0;
            *(float4*)&Bs[bk * 68 + bn0]     = *(const float4*)bp;
            *(float4*)&Bs[bk * 68 + bn0 + 4] = *(const float4*)(bp + 4);
        }
        __syncthreads();
#pragma unroll 4
        for (int kk = 0; kk < 32; kk++) {
            float2 av = *(const float2*)&AsT[kk * 18 + rg * 2];
            float2 bv = *(const float2*)&Bs[kk * 68 + cg * 2];
            acc[0][0] += av.x * bv.x; acc[0][1] += av.x * bv.y;
            acc[1][0] += av.y * bv.x; acc[1][1] += av.y * bv.y;
        }
        __syncthreads();
    }
    bool rnd = (t == 0 && modes[0] == 0 && modes[3] == 0);
#pragma unroll
    for (int i = 0; i < 2; i++)
#pragma unroll
        for (int j = 0; j < 2; j++) {
            int f = cg * 2 + j;
            float v = (rnd ? r16(acc[i][j]) : acc[i][j]) + bf(bg, f);
            dfT[f * 18 + rg * 2 + i] = v;
        }
    __syncthreads();
    // merged: de1 = tanh(dfT^T @ W1 + b1), de2 = tanh(dfT^T @ W2 + b2)
    float a1[2][2] = {};
    float a2[2][2] = {};
    for (int kb2 = 0; kb2 < 64; kb2 += 32) {
        int bk = tid >> 3, bn0 = (tid & 7) * 8;
        const float* bp1 = W1f + (size_t)(kb2 + bk) * 64 + bn0;
        const float* bp2 = W2f + (size_t)(kb2 + bk) * 64 + bn0;
        *(float4*)&Bs[bk * 68 + bn0]            = *(const float4*)bp1;
        *(float4*)&Bs[bk * 68 + bn0 + 4]        = *(const float4*)(bp1 + 4);
        *(float4*)&Bs[2176 + bk * 68 + bn0]     = *(const float4*)bp2;
        *(float4*)&Bs[2176 + bk * 68 + bn0 + 4] = *(const float4*)(bp2 + 4);
        __syncthreads();
#pragma unroll 4
        for (int kk = 0; kk < 32; kk++) {
            float2 av  = *(const float2*)&dfT[(kb2 + kk) * 18 + rg * 2];
            float2 b1v = *(const float2*)&Bs[kk * 68 + cg * 2];
            float2 b2v = *(const float2*)&Bs[2176 + kk * 68 + cg * 2];
            a1[0][0] += av.x * b1v.x; a1[0][1] += av.x * b1v.y;
            a1[1][0] += av.y * b1v.x; a1[1][1] += av.y * b1v.y;
            a2[0][0] += av.x * b2v.x; a2[0][1] += av.x * b2v.y;
            a2[1][0] += av.y * b2v.x; a2[1][1] += av.y * b2v.y;
        }
        __syncthreads();
    }
#pragma unroll
    for (int i = 0; i < 2; i++) {
        int row = b * NN + c0 + rg * 2 + i;
        float2 o1, o2;
        o1.x = tanh_s(a1[i][0] + bf(b1, cg * 2 + 0));
        o1.y = tanh_s(a1[i][1] + bf(b1, cg * 2 + 1));
        o2.x = tanh_s(a2[i][0] + bf(b2, cg * 2 + 0));
        o2.y = tanh_s(a2[i][1] + bf(b2, cg * 2 + 1));
        *(float2*)&de1[(size_t)row * 64 + cg * 2] = o1;
        *(float2*)&de2[(size_t)row * 64 + cg * 2] = o2;
    }
}

// k45: fused M+Et+hist+AhT+qsum. grid (4,4,BB): r0=bx*64, c0=by*64. (R12 form)
__global__ __launch_bounds__(256) void k45(const float* de1, const float* de2,
                                           float* hist, float* AhT, float* qsum,
                                           int slabW, int slabR, float inv_cnt) {
    __shared__ float As[32][68];
    __shared__ float Bs[32][68];
    __shared__ float m2b[64][65];
    __shared__ float qpart[64];
    int b = blockIdx.z, r0 = blockIdx.x * 64, c0 = blockIdx.y * 64;
    int tid = threadIdx.x;
    if (tid < 64) qpart[tid] = 0.f;
    int tn = tid & 15, tm = tid >> 4;
    int am = tid >> 2, ak0 = (tid & 3) * 8;
    int rot = (tid & 3) * 2;
    const float* d1 = de1 + (size_t)b * (NN * EMBD);
    const float* d2 = de2 + (size_t)b * (NN * EMBD);
    // GEMM-A: M2[cl][rl] = de1[c0+cl]·de2[r0+rl]
    float acc2[4][4] = {};
    for (int kb = 0; kb < 64; kb += 32) {
        const float* ap = d1 + (size_t)(c0 + am) * 64 + kb + ak0;
        float4 a0 = *(const float4*)ap;
        float4 a1 = *(const float4*)(ap + 4);
        float av8[8] = {a0.x, a0.y, a0.z, a0.w, a1.x, a1.y, a1.z, a1.w};
#pragma unroll
        for (int jj = 0; jj < 8; jj++) { int j = (jj + rot) & 7; As[ak0 + j][am] = av8[j]; }
        const float* bp = d2 + (size_t)(r0 + am) * 64 + kb + ak0;
        float4 b0 = *(const float4*)bp;
        float4 b1v = *(const float4*)(bp + 4);
        float bv8[8] = {b0.x, b0.y, b0.z, b0.w, b1v.x, b1v.y, b1v.z, b1v.w};
#pragma unroll
        for (int jj = 0; jj < 8; jj++) { int j = (jj + rot) & 7; Bs[ak0 + j][am] = bv8[j]; }
        __syncthreads();
#pragma unroll
        for (int kk = 0; kk < 32; kk++) {
            float4 av = *(const float4*)&As[kk][tm * 4];
            float4 bv = *(const float4*)&Bs[kk][tn * 4];
            float aa[4] = {av.x, av.y, av.z, av.w};
            float bb[4] = {bv.x, bv.y, bv.z, bv.w};
#pragma unroll
            for (int i = 0; i < 4; i++)
#pragma unroll
                for (int j = 0; j < 4; j++) acc2[i][j] += aa[i] * bb[j];
        }
        __syncthreads();
    }
#pragma unroll
    for (int i = 0; i < 4; i++)
#pragma unroll
        for (int j = 0; j < 4; j++) m2b[tm * 4 + i][tn * 4 + j] = acc2[i][j];
    // GEMM-B: M1[rl][cl] = de1[r0+rl]·de2[c0+cl]
    float acc1[4][4] = {};
    for (int kb = 0; kb < 64; kb += 32) {
        const float* ap = d1 + (size_t)(r0 + am) * 64 + kb + ak0;
        float4 a0 = *(const float4*)ap;
        float4 a1 = *(const float4*)(ap + 4);
        float av8[8] = {a0.x, a0.y, a0.z, a0.w, a1.x, a1.y, a1.z, a1.w};
#pragma unroll
        for (int jj = 0; jj < 8; jj++) { int j = (jj + rot) & 7; As[ak0 + j][am] = av8[j]; }
        const float* bp = d2 + (size_t)(c0 + am) * 64 + kb + ak0;
        float4 b0 = *(const float4*)bp;
        float4 b1v = *(const float4*)(bp + 4);
        float bv8[8] = {b0.x, b0.y, b0.z, b0.w, b1v.x, b1v.y, b1v.z, b1v.w};
#pragma unroll
        for (int jj = 0; jj < 8; jj++) { int j = (jj + rot) & 7; Bs[ak0 + j][am] = bv8[j]; }
        __syncthreads();
#pragma unroll
        for (int kk = 0; kk < 32; kk++) {
            float4 av = *(const float4*)&As[kk][tm * 4];
            float4 bv = *(const float4*)&Bs[kk][tn * 4];
            float aa[4] = {av.x, av.y, av.z, av.w};
            float bb[4] = {bv.x, bv.y, bv.z, bv.w};
#pragma unroll
            for (int i = 0; i < 4; i++)
#pragma unroll
                for (int j = 0; j < 4; j++) acc1[i][j] += aa[i] * bb[j];
        }
        __syncthreads();
    }
    // Et + hist roll + ad; hist I/O float4 along c
    size_t NB = (size_t)BB * NN * NN;
    float* hsW = hist + (size_t)slabW * NB;
    const float* hsR = hist + (size_t)slabR * NB;
    float ad[4][4];
#pragma unroll
    for (int i = 0; i < 4; i++) {
        int r = r0 + tm * 4 + i;
        size_t o = ((size_t)(b * NN + r)) * NN + c0 + tn * 4;
        float4 e2v = *(const float4*)&hsW[o];
        float4 e1v = *(const float4*)&hsR[o];
        float e2a[4] = {e2v.x, e2v.y, e2v.z, e2v.w};
        float e1a[4] = {e1v.x, e1v.y, e1v.z, e1v.w};
        float4 ew4;
        float eo[4];
#pragma unroll
        for (int j = 0; j < 4; j++) {
            int c = c0 + tn * 4 + j;
            float e = tanh_s(acc1[i][j] - m2b[tn * 4 + j][tm * 4 + i]);
            e = e > 0.f ? e : 0.f;
            eo[j] = e;
            float mt = (e + e1a[j] + e2a[j]) * inv_cnt;
            float adv = (mt > 1e-8f) ? mt : 0.f;
            if (r == c) adv += 1.f;
            ad[i][j] = adv;
        }
        ew4.x = eo[0]; ew4.y = eo[1]; ew4.z = eo[2]; ew4.w = eo[3];
        *(float4*)&hsW[o] = ew4;
    }
    // qsum partials: column sums over this tile's rows
#pragma unroll
    for (int j = 0; j < 4; j++) {
        float cs = ad[0][j] + ad[1][j] + ad[2][j] + ad[3][j];
        atomicAdd(&qpart[tn * 4 + j], cs);
    }
    // stage ad transposed for coalesced AhT write (reuse m2b after all reads)
    __syncthreads();
#pragma unroll
    for (int i = 0; i < 4; i++)
#pragma unroll
        for (int j = 0; j < 4; j++) m2b[tn * 4 + j][tm * 4 + i] = ad[i][j];
    __syncthreads();
#pragma unroll
    for (int kk = 0; kk < 4; kk++) {
        int e = tid + kk * 256;
        int cl = e >> 4, q4 = e & 15;
        float4 o;
        o.x = m2b[cl][q4 * 4 + 0]; o.y = m2b[cl][q4 * 4 + 1];
        o.z = m2b[cl][q4 * 4 + 2]; o.w = m2b[cl][q4 * 4 + 3];
        *(float4*)&AhT[((size_t)(b * NN + c0 + cl)) * NN + r0 + q4 * 4] = o;
    }
    if (tid < 64) atomicAdd(&qsum[b * NN + c0 + tid], qpart[tid]);
}

// kZRH16: fused G + GRU + next-step Y. grid 512: 16 rows/block (2 blocks/CU).
// (unchanged from R14)
__global__ __launch_bounds__(256) void kZRH16(const float* AhT, const float* qsum, float* h,
                                              const float* Wf, const float* bfv,
                                              const float* Wgf, const void* x, float* Y,
                                              int t, const int* modes) {
    __shared__ float qrow[256];
    __shared__ float As[160 * 20];   // [k][row], 16 rows, stride 20
    __shared__ float pool[10496];    // Bs[0..8448) + zbuf[8448..10496); Y: Wgf[0..10240)
    float* Bs   = pool;
    float* zbuf = pool + 8448;       // [16][128]
    int r0 = blockIdx.x * 16;        // global row (b*NN + n)
    int b  = r0 >> 8;
    int tid = threadIdx.x;
    int m0 = modes[0];
    // stage h^T: h[r0+r][c] -> As[(32+c)*20 + r]
#pragma unroll
    for (int u = 0; u < 2; u++) {
        int e = tid * 2 + u;
        int r = e >> 5, c4 = (e & 31) * 4;
        float4 hv = *(const float4*)&h[(size_t)(r0 + r) * 128 + c4];
        As[(32 + c4 + 0) * 20 + r] = hv.x;
        As[(32 + c4 + 1) * 20 + r] = hv.y;
        As[(32 + c4 + 2) * 20 + r] = hv.z;
        As[(32 + c4 + 3) * 20 + r] = hv.w;
    }
    qrow[tid] = 1.0f / sqrtf(fmaxf(qsum[b * NN + tid], 1e-12f));
    __syncthreads();

    // ---- phase 0: G into As G-region ----
    {
        float* vtq = Bs;            // [32 w][132 r]
        float* Ah  = Bs + 4224;     // [16][132]
        float gacc[2] = {0.f, 0.f};
        int gi = tid & 15, gw = (tid >> 4) * 2;
        for (int half = 0; half < 2; half++) {
            int wv = tid & 31, rb = tid >> 5;
#pragma unroll
            for (int k = 0; k < 16; k++) {
                int rl = rb + 8 * k;
                int rg = half * 128 + rl;
                vtq[wv * 132 + rl] = qrow[rg] * ld3(x, (b * NN + rg) * TT + t * WW + wv, m0);
            }
            {
                int i = tid >> 4, c8 = (tid & 15) * 8;
                const float* ap = AhT + (size_t)(r0 + i) * NN + half * 128 + c8;
                *(float4*)&Ah[i * 132 + c8]     = *(const float4*)ap;
                *(float4*)&Ah[i * 132 + c8 + 4] = *(const float4*)(ap + 4);
            }
            __syncthreads();
            for (int r = 0; r < 128; r += 4) {
                float4 a  = *(const float4*)&Ah[gi * 132 + r];
                float4 v0 = *(const float4*)&vtq[gw * 132 + r];
                float4 v1 = *(const float4*)&vtq[(gw + 1) * 132 + r];
                gacc[0] += a.x * v0.x;
                gacc[1] += a.x * v1.x;
                gacc[0] += a.y * v0.y;
                gacc[1] += a.y * v1.y;
                gacc[0] += a.z * v0.z;
                gacc[1] += a.z * v1.z;
                gacc[0] += a.w * v0.w;
                gacc[1] += a.w * v1.w;
            }
            __syncthreads();
        }
        float qc = qrow[(r0 & 255) + gi];
        As[gw * 20 + gi]       = qc * gacc[0];
        As[(gw + 1) * 20 + gi] = qc * gacc[1];
        // gates stage Bs then sync before reading As G-region
    }

    // ---- gates: role-split. tid<128 -> Z, tid>=128 -> R. 4r x 4c tiles. ----
    {
        int gsel = tid >> 7;                 // 0 = Z, 1 = R
        int rt = (tid >> 5) & 3;             // rows rt*4+i
        int ct = tid & 31;                   // cols ct*4+j
        const float* W0 = Wf;
        const float* W1 = Wf + (size_t)(160 * 128);
        float accG[4][4] = {};
        for (int kb = 0; kb < 160; kb += 32) {
#pragma unroll
            for (int u = 0; u < 4; u++) {
                int e = tid + u * 256;
                int kk = e >> 5, c4 = (e & 31) * 4;
                *(float4*)&Bs[kk * 128 + c4]        = *(const float4*)&W0[(size_t)(kb + kk) * 128 + c4];
                *(float4*)&Bs[4096 + kk * 128 + c4] = *(const float4*)&W1[(size_t)(kb + kk) * 128 + c4];
            }
            __syncthreads();
            const float* Bp = Bs + gsel * 4096;
#pragma unroll 4
            for (int kk = 0; kk < 32; kk++) {
                float4 av = *(const float4*)&As[(kb + kk) * 20 + rt * 4];
                float4 bv = *(const float4*)&Bp[kk * 128 + ct * 4];
                accG[0][0] += av.x * bv.x; accG[0][1] += av.x * bv.y;
                accG[0][2] += av.x * bv.z; accG[0][3] += av.x * bv.w;
                accG[1][0] += av.y * bv.x; accG[1][1] += av.y * bv.y;
                accG[1][2] += av.y * bv.z; accG[1][3] += av.y * bv.w;
                accG[2][0] += av.z * bv.x; accG[2][1] += av.z * bv.y;
                accG[2][2] += av.z * bv.z; accG[2][3] += av.z * bv.w;
                accG[3][0] += av.w * bv.x; accG[3][1] += av.w * bv.y;
                accG[3][2] += av.w * bv.z; accG[3][3] += av.w * bv.w;
            }
            __syncthreads();
        }
        if (gsel == 0) {
            // Z -> zbuf
#pragma unroll
            for (int i = 0; i < 4; i++)
#pragma unroll
                for (int j = 0; j < 4; j++)
                    zbuf[(rt * 4 + i) * 128 + ct * 4 + j] =
                        sig_s(accG[i][j] + bfv[ct * 4 + j]);
        } else {
            // R -> hR in place (each slot owned by exactly one thread)
#pragma unroll
            for (int i = 0; i < 4; i++)
#pragma unroll
                for (int j = 0; j < 4; j++) {
                    float rv = sig_s(accG[i][j] + bfv[128 + ct * 4 + j]);
                    int slot = (32 + ct * 4 + j) * 20 + rt * 4 + i;
                    As[slot] = As[slot] * rv;
                }
        }
        // next phase's staging + sync orders these writes before any read
    }

    int rg = tid >> 5, cg = tid & 31;   // 2r x 4c for Ht / h-update
    // ---- Ht GEMM over [G|hR] (panel 0 of Bs) ----
    float acc[2][4] = {};
    {
        const float* Wgp = Wf + (size_t)2 * (160 * 128);
        for (int kb = 0; kb < 160; kb += 32) {
#pragma unroll
            for (int u = 0; u < 4; u++) {
                int e = tid + u * 256;
                int kk = e >> 5, c4 = (e & 31) * 4;
                *(float4*)&Bs[kk * 128 + c4] = *(const float4*)&Wgp[(size_t)(kb + kk) * 128 + c4];
            }
            __syncthreads();
#pragma unroll 4
            for (int kk = 0; kk < 32; kk++) {
                float2 av = *(const float2*)&As[(kb + kk) * 20 + rg * 2];
                float4 bv = *(const float4*)&Bs[kk * 128 + cg * 4];
                acc[0][0] += av.x * bv.x; acc[0][1] += av.x * bv.y;
                acc[0][2] += av.x * bv.z; acc[0][3] += av.x * bv.w;
                acc[1][0] += av.y * bv.x; acc[1][1] += av.y * bv.y;
                acc[1][2] += av.y * bv.z; acc[1][3] += av.y * bv.w;
            }
            __syncthreads();
        }
    }
    // ---- h-update; write h global + refresh As h-region with h_new ----
#pragma unroll
    for (int i = 0; i < 2; i++) {
        int row = r0 + rg * 2 + i;
        size_t o = (size_t)row * 128 + cg * 4;
        float4 hv = *(const float4*)&h[o];       // h_old (global still intact)
        float4 zq = *(const float4*)&zbuf[(rg * 2 + i) * 128 + cg * 4];
        float4 r;
        r.x = zq.x * hv.x + (1.0f - zq.x) * tanh_s(acc[i][0] + bfv[256 + cg * 4 + 0]);
        r.y = zq.y * hv.y + (1.0f - zq.y) * tanh_s(acc[i][1] + bfv[256 + cg * 4 + 1]);
        r.z = zq.z * hv.z + (1.0f - zq.z) * tanh_s(acc[i][2] + bfv[256 + cg * 4 + 2]);
        r.w = zq.w * hv.w + (1.0f - zq.w) * tanh_s(acc[i][3] + bfv[256 + cg * 4 + 3]);
        *(float4*)&h[o] = r;
        As[(32 + cg * 4 + 0) * 20 + rg * 2 + i] = r.x;
        As[(32 + cg * 4 + 1) * 20 + rg * 2 + i] = r.y;
        As[(32 + cg * 4 + 2) * 20 + rg * 2 + i] = r.z;
        As[(32 + cg * 4 + 3) * 20 + rg * 2 + i] = r.w;
    }
    // ---- next-step Y = [vt(t+1)|h_new] @ Wgf (full Wgf resident; no inner barriers) ----
    if (t < 7) {
        __syncthreads();   // zbuf reads + As h-writes complete before pool overwrite
        // stage vt2^T into the dead G-region
#pragma unroll
        for (int u = 0; u < 2; u++) {
            int e = tid * 2 + u;
            int r = e >> 5, w = e & 31;
            As[w * 20 + r] = ld3(x, (r0 + r) * TT + (t + 1) * WW + w, m0);
        }
        // preload ALL of Wgf: 10240 floats = 2560 float4, 10 per thread
#pragma unroll
        for (int u = 0; u < 10; u++) {
            int e = tid + u * 256;
            *(float4*)&pool[e * 4] = *(const float4*)&Wgf[(size_t)e * 4];
        }
        __syncthreads();
        int yr = tid >> 4, yc4 = (tid & 15) * 4;
        float yacc[4] = {0.f, 0.f, 0.f, 0.f};
#pragma unroll 8
        for (int k = 0; k < 160; k++) {
            float a = As[k * 20 + yr];
            float4 bv = *(const float4*)&pool[k * 64 + yc4];
            yacc[0] += a * bv.x; yacc[1] += a * bv.y;
            yacc[2] += a * bv.z; yacc[3] += a * bv.w;
        }
        *(float4*)&Y[(size_t)(r0 + yr) * 64 + yc4] =
            make_float4(yacc[0], yacc[1], yacc[2], yacc[3]);
    }
}

__global__ __launch_bounds__(256) void k10a(const float* h, const float* Wcf, float* partial) {
    __shared__ float red[16][17];
    int chunk = blockIdx.x, b = blockIdx.y;
    int c = threadIdx.x & 15, isub = threadIdx.x >> 4;
    const float* hb = h + (size_t)b * (NN * HH);
    int i0 = chunk * 2048;
    float acc = 0.f;
    for (int s = 0; s < 128; s++) {
        int i = i0 + isub + 16 * s;
        acc += hb[i] * Wcf[(size_t)i * NCLS + c];
    }
    red[isub][c] = acc;
    __syncthreads();
    for (int st = 8; st > 0; st >>= 1) {
        if (isub < st) red[isub][c] += red[isub + st][c];
        __syncthreads();
    }
    if (isub == 0) partial[((size_t)(b * NCLS + c)) * 16 + chunk] = red[0][c];
}

__global__ __launch_bounds__(512) void k10b(const float* partial, const __hip_bfloat16* bcb,
                                            float* out) {
    int tid = threadIdx.x;
    if (tid < BB * NCLS) {
        int c = tid & 15;
        float s = 0.f;
        for (int k = 0; k < 16; k++) s += partial[(size_t)tid * 16 + k];
        out[tid] = s + bf(bcb, c);
    }
}

// ---------------- launch ----------------

extern "C" void kernel_launch(void* const* d_in, const int* in_sizes, int n_in,
                              void* d_out, int out_size, void* d_ws, size_t ws_size,
                              hipStream_t stream) {
    float* out = (float*)d_out;

    static const int exp_sizes[23] = {2097152, 16384, 8192, 10240, 64, 4096, 64, 4096, 64,
                                      4096, 128, 4096, 128, 4096, 128, 32768, 128, 32768, 128,
                                      32768, 128, 524288, 16};
    if (n_in != 23) { k_sentinel<<<8, 64, 0, stream>>>(out, 4444.0f); return; }
    for (int i = 0; i < 23; i++) {
        if (in_sizes[i] != exp_sizes[i]) {
            k_sentinel<<<8, 64, 0, stream>>>(out, (float)(4000 + i));
            return;
        }
    }

    const void* x   = d_in[0];
    const int*  ei  = (const int*)d_in[1];
    const void* ew  = d_in[2];
    const void* Wg  = d_in[3];
    const __hip_bfloat16* bg  = (const __hip_bfloat16*)d_in[4];
    const void* W1  = d_in[5];
    const __hip_bfloat16* b1  = (const __hip_bfloat16*)d_in[6];
    const void* W2  = d_in[7];
    const __hip_bfloat16* b2  = (const __hip_bfloat16*)d_in[8];
    const void* Wz  = d_in[9];
    const __hip_bfloat16* bz  = (const __hip_bfloat16*)d_in[10];
    const void* Wr  = d_in[11];
    const __hip_bfloat16* br  = (const __hip_bfloat16*)d_in[12];
    const void* Wh  = d_in[13];
    const __hip_bfloat16* bh  = (const __hip_bfloat16*)d_in[14];
    const void* Wlz = d_in[15];
    const __hip_bfloat16* blz = (const __hip_bfloat16*)d_in[16];
    const void* Wlr = d_in[17];
    const __hip_bfloat16* blr = (const __hip_bfloat16*)d_in[18];
    const void* Wlh = d_in[19];
    const __hip_bfloat16* blh = (const __hip_bfloat16*)d_in[20];
    const void* Wc  = d_in[21];
    const __hip_bfloat16* bcb = (const __hip_bfloat16*)d_in[22];

    float* ws = (float*)d_ws;
    const size_t off_A    = 0;                          // 65536
    const size_t off_hist = off_A + 65536;              // 2*2097152
    const size_t off_h    = off_hist + 2u * 2097152;    // 1048576
    const size_t off_flag = off_h + 1048576;            // 16
    const size_t off_mode = off_flag + 16;              // 32
    const size_t off_insB = off_mode + 32;              // 32
    const size_t off_insF = off_insB + 32;              // 32
    const size_t zero_end = off_insF + 32;
    const size_t off_St   = zero_end;                   // 65536
    const size_t off_di   = off_St + 65536;             // 256
    const size_t off_q    = off_di + 256;               // 8192 (qsum; k10 partial after)
    const size_t off_AhT  = off_q + 8192;               // 2097152
    const size_t off_Yp   = off_AhT + 2097152;          // 3145728 scratch region
    const size_t off_C    = off_Yp + 3145728;           // (fused Wf/bfv)
    const size_t off_wts  = off_C + 3145728;            // 665600
    const size_t need_bytes = (off_wts + 665600u) * sizeof(float);

    if (ws_size < need_bytes) {
        k_sentinel<<<8, 64, 0, stream>>>(out, (float)ws_size);
        return;
    }

    float* A    = ws + off_A;
    float* hist = ws + off_hist;
    float* h    = ws + off_h;
    int*   modes= (int*)(ws + off_mode);
    int*   insB = (int*)(ws + off_insB);
    int*   insF = (int*)(ws + off_insF);
    float* St   = ws + off_St;
    float* di   = ws + off_di;
    float* qsum = ws + off_q;
    float* AhT  = ws + off_AhT;
    float* wts  = ws + off_wts;
    // scratch lifetimes (one step):
    //   Y   [0,524288)         kZRH16(t-1)/k1 -> k23h
    //   de1 [1048576,1572864)  k23h -> k45
    //   de2 [1572864,2097152)  k23h -> k45
    float* Y    = ws + off_Yp;
    float* de1  = ws + off_Yp + 1048576;
    float* de2  = ws + off_Yp + 1572864;
    float* Wf   = ws + off_C;            // [3][160][128] = 61440
    float* bfv  = ws + off_C + 61440;    // [3][128] = 384
    float* partial = qsum;   // qsum dead after last kZRH16

    float* Wgf  = wts;
    float* W1f  = wts + 10240;
    float* W2f  = wts + 14336;
    float* Wzf  = wts + 18432;
    float* Wrf  = wts + 22528;
    float* Whf  = wts + 26624;
    float* Wlzf = wts + 30720;
    float* Wlrf = wts + 63488;
    float* Wlhf = wts + 96256;
    float* Wcf  = wts + 129024;

    hipMemsetAsync(ws, 0, zero_end * sizeof(float), stream);

    k_probe_all<<<48, 256, 0, stream>>>(x, ew, Wg, W1, W2, Wz, Wr, Wh, Wlz, Wlr, Wlh, Wc,
                                        insB, insF);
    k_resolve<<<1, 32, 0, stream>>>(insB, insF, modes);
    k_detect_ei<<<1, 64, 0, stream>>>(ei, modes);
    k_cvtall<<<2600, 256, 0, stream>>>(Wg, W1, W2, Wz, Wr, Wh, Wlz, Wlr, Wlh, Wc, modes, wts);
    k_fuse<<<dim3(80, 3), 256, 0, stream>>>(Wzf, Wrf, Whf, Wlzf, Wlrf, Wlhf,
                                            bz, br, bh, blz, blr, blh, Wf, bfv);

    k_scatter<<<NE / 256, 256, 0, stream>>>(ei, ew, A, modes);
    k_roundA<<<NN * NN / 256, 256, 0, stream>>>(A);
    k_di<<<NN / 4, 256, 0, stream>>>(A, di);
    k_St<<<NN * NN / 256, 256, 0, stream>>>(A, di, St);

    for (int t = 0; t < 8; t++) {
        if (t == 0)
            k1_itwg4<<<dim3(NN / 4, BB), 256, 0, stream>>>(x, h, Wgf, Y, 0, modes);
        k23h<<<dim3(NN / 16, BB), 256, 0, stream>>>(St, Y, bg, W1f, W2f, b1, b2,
                                                    de1, de2, qsum, t, modes);
        float inv_cnt = 1.0f / (float)((t + 1 < 3) ? (t + 1) : 3);
        k45<<<dim3(4, 4, BB), 256, 0, stream>>>(de1, de2, hist, AhT, qsum,
                                                t & 1, (t + 1) & 1, inv_cnt);
        kZRH16<<<NN * BB / 16, 256, 0, stream>>>(AhT, qsum, h, Wf, bfv, Wgf, x, Y, t, modes);
    }

    k10a<<<dim3(16, BB), 256, 0, stream>>>(h, Wcf, partial);
    k10b<<<1, 512, 0, stream>>>(partial, bcb, out);
}